// Round 1
// baseline (1097.310 us; speedup 1.0000x reference)
//
#include <hip/hip_runtime.h>
#include <math.h>

// ---------------------------------------------------------------------------
// dual GAT (2 branches x 4 GATConv layers), N=20000 nodes, E=320000 edges.
// Strategy: per branch build CSR by dst once (shared by all 4 layers), then
// per layer: GEMM h=xW (LDS-staged W), per-node scores, CSR-gather aggregate
// with in-register softmax (no float atomics).
// ---------------------------------------------------------------------------

#define WAVE 64

__global__ void zero_ints(int* __restrict__ p, int n) {
    int t = blockIdx.x * blockDim.x + threadIdx.x;
    if (t < n) p[t] = 0;
}

// count in-degree over E real edges + n self loops
__global__ void count_deg(const int* __restrict__ ei, int* __restrict__ deg,
                          int n, int E) {
    int t = blockIdx.x * blockDim.x + threadIdx.x;
    int total = E + n;
    if (t >= total) return;
    int dst = (t < E) ? ei[E + t] : (t - E);
    atomicAdd(&deg[dst], 1);
}

// single-block exclusive scan of deg -> rowptr, also copy to cursor
__global__ void scan_rowptr(const int* __restrict__ deg, int* __restrict__ rowptr,
                            int* __restrict__ cursor, int n) {
    __shared__ int smem[256];
    __shared__ int s_running;
    if (threadIdx.x == 0) s_running = 0;
    __syncthreads();
    int nChunks = (n + 255) / 256;
    for (int ch = 0; ch < nChunks; ++ch) {
        int i = ch * 256 + threadIdx.x;
        int v = (i < n) ? deg[i] : 0;
        smem[threadIdx.x] = v;
        __syncthreads();
        #pragma unroll
        for (int off = 1; off < 256; off <<= 1) {
            int t = (threadIdx.x >= off) ? smem[threadIdx.x - off] : 0;
            __syncthreads();
            smem[threadIdx.x] += t;
            __syncthreads();
        }
        int incl = smem[threadIdx.x];
        int excl = incl - v;
        int base = s_running;
        if (i < n) { rowptr[i] = base + excl; cursor[i] = base + excl; }
        __syncthreads();
        if (threadIdx.x == 255) s_running = base + incl;
        __syncthreads();
    }
    if (threadIdx.x == 0) rowptr[n] = s_running;
}

__global__ void fill_csr(const int* __restrict__ ei, int* __restrict__ cursor,
                         int* __restrict__ csr_edges, int n, int E) {
    int t = blockIdx.x * blockDim.x + threadIdx.x;
    int total = E + n;
    if (t >= total) return;
    int dst = (t < E) ? ei[E + t] : (t - E);
    int pos = atomicAdd(&cursor[dst], 1);
    csr_edges[pos] = t;
}

// h = x @ W  for F_IN=128, f_out in {64,128}. Block = 256 threads (4 waves),
// each block owns a 64-col slice (blockIdx.y) and 4 rows per iteration.
__global__ __launch_bounds__(256) void gemm128(const float* __restrict__ x,
                                               const float* __restrict__ W,
                                               float* __restrict__ h,
                                               int n, int f_out) {
    __shared__ float Wlds[128 * 64];
    __shared__ float xlds[4 * 128];
    int colbase = blockIdx.y * 64;
    int lane = threadIdx.x & 63;
    int wid  = threadIdx.x >> 6;
    for (int i = threadIdx.x; i < 128 * 64; i += 256)
        Wlds[i] = W[(i >> 6) * f_out + colbase + (i & 63)];
    for (int base = blockIdx.x * 4; base < n; base += gridDim.x * 4) {
        __syncthreads();
        for (int i = threadIdx.x; i < 4 * 128; i += 256) {
            int rr = base + (i >> 7);
            xlds[i] = (rr < n) ? x[rr * 128 + (i & 127)] : 0.f;
        }
        __syncthreads();
        int row = base + wid;
        float acc = 0.f;
        #pragma unroll
        for (int k = 0; k < 128; ++k)
            acc = fmaf(xlds[wid * 128 + k], Wlds[k * 64 + lane], acc);
        if (row < n) h[row * f_out + colbase + lane] = acc;
    }
}

// s_src[n,hd] = dot(h[n,hd,:], a_s[hd]);  s_dst likewise with a_d
template <int HEADS, int C>
__global__ void node_scores(const float* __restrict__ h,
                            const float* __restrict__ a_s,
                            const float* __restrict__ a_d,
                            float* __restrict__ s_src,
                            float* __restrict__ s_dst, int n) {
    int t = blockIdx.x * blockDim.x + threadIdx.x;
    if (t >= n * HEADS) return;
    int node = t / HEADS, hd = t % HEADS;
    const float* hp = h + node * (HEADS * C) + hd * C;
    const float* as = a_s + hd * C;
    const float* ad = a_d + hd * C;
    float ss = 0.f, sd = 0.f;
    #pragma unroll 8
    for (int c = 0; c < C; ++c) {
        float hv = hp[c];
        ss = fmaf(hv, as[c], ss);
        sd = fmaf(hv, ad[c], sd);
    }
    s_src[t] = ss;
    s_dst[t] = sd;
}

// One wave per destination node. MODE 0: relu -> out (next x).
// MODE 1: 0.5*sigmoid -> d_out (store).  MODE 2: 0.5*sigmoid -> d_out (+=).
template <int HEADS, int C, int MODE>
__global__ __launch_bounds__(256) void aggregate(
        const float* __restrict__ h, const float* __restrict__ s_src,
        const float* __restrict__ s_dst, const int* __restrict__ rowptr,
        const int* __restrict__ csr_edges, const int* __restrict__ ei_src,
        const float* __restrict__ bias, float* __restrict__ out,
        int n, int E) {
    constexpr int OUTW = HEADS * C;
    constexpr int CPL = (OUTW + WAVE - 1) / WAVE;   // cols per lane (2 or 1)
    int wid = threadIdx.x >> 6;
    int lane = threadIdx.x & 63;
    int v = blockIdx.x * (blockDim.x >> 6) + wid;
    if (v >= n) return;
    int beg = rowptr[v], end = rowptr[v + 1];

    float sd[HEADS];
    #pragma unroll
    for (int hd = 0; hd < HEADS; ++hd) sd[hd] = s_dst[v * HEADS + hd];

    // pass 1: per-head max over in-edges (leaky-relu'd scores)
    float mx[HEADS];
    #pragma unroll
    for (int hd = 0; hd < HEADS; ++hd) mx[hd] = -1e30f;
    for (int i = beg + lane; i < end; i += WAVE) {
        int e = csr_edges[i];
        int s = (e < E) ? ei_src[e] : (e - E);
        #pragma unroll
        for (int hd = 0; hd < HEADS; ++hd) {
            float sc = s_src[s * HEADS + hd] + sd[hd];
            sc = (sc >= 0.f) ? sc : 0.2f * sc;
            mx[hd] = fmaxf(mx[hd], sc);
        }
    }
    #pragma unroll
    for (int hd = 0; hd < HEADS; ++hd) {
        float m = mx[hd];
        #pragma unroll
        for (int off = 32; off >= 1; off >>= 1)
            m = fmaxf(m, __shfl_xor(m, off, WAVE));
        mx[hd] = m;
    }

    // pass 2: serial over edges, lanes = output columns
    float acc[CPL], den[CPL];
    #pragma unroll
    for (int c = 0; c < CPL; ++c) { acc[c] = 0.f; den[c] = 0.f; }
    for (int i = beg; i < end; ++i) {
        int e = csr_edges[i];                    // wave-uniform
        int s = (e < E) ? ei_src[e] : (e - E);
        #pragma unroll
        for (int c = 0; c < CPL; ++c) {
            int col = lane + WAVE * c;
            int hd = col / C;
            float sc = s_src[s * HEADS + hd] + sd[hd];
            sc = (sc >= 0.f) ? sc : 0.2f * sc;
            float w = __expf(sc - mx[hd]);
            den[c] += w;
            acc[c] = fmaf(w, h[s * OUTW + col], acc[c]);
        }
    }

    #pragma unroll
    for (int c = 0; c < CPL; ++c) {
        int col = lane + WAVE * c;
        float o = acc[c] / den[c] + bias[col];
        if (MODE == 0) {
            out[v * OUTW + col] = fmaxf(o, 0.f);
        } else {
            float sg = 0.5f / (1.f + __expf(-o));
            if (MODE == 1) out[v * 64 + col] = sg;
            else           out[v * 64 + col] += sg;
        }
    }
}

extern "C" void kernel_launch(void* const* d_in, const int* in_sizes, int n_in,
                              void* d_out, int out_size, void* d_ws, size_t ws_size,
                              hipStream_t stream) {
    const int N = in_sizes[0] / 128;      // 20000
    const int E = in_sizes[1] / 2;        // 320000
    const int TOT = E + N;                // edges incl. self loops

    const float* x1 = (const float*)d_in[0];
    const int*   ei1 = (const int*)d_in[1];
    const float* x2 = (const float*)d_in[2];
    const int*   ei2 = (const int*)d_in[3];

    // workspace layout
    char* w = (char*)d_ws;
    float* bufX = (float*)w;           w += (size_t)N * 128 * 4;
    float* bufH = (float*)w;           w += (size_t)N * 128 * 4;
    float* s_src = (float*)w;          w += (size_t)N * 4 * 4;
    float* s_dst = (float*)w;          w += (size_t)N * 4 * 4;
    int* rowptr = (int*)w;             w += (size_t)(N + 1) * 4 + 12;
    int* cursor = (int*)w;             w += (size_t)N * 4;
    int* deg = (int*)w;                w += (size_t)N * 4;
    int* csr = (int*)w;                w += (size_t)TOT * 4;

    dim3 blk(256);
    int gEdges = (TOT + 255) / 256;
    int gNodes = (N + 255) / 256;
    int gAgg = (N + 3) / 4;

    for (int b = 0; b < 2; ++b) {
        const float* x = b ? x2 : x1;
        const int* ei = b ? ei2 : ei1;
        void* const* P = d_in + (b ? 20 : 4);

        // ---- CSR build (shared across the 4 layers of this branch)
        zero_ints<<<gNodes, blk, 0, stream>>>(deg, N);
        count_deg<<<gEdges, blk, 0, stream>>>(ei, deg, N, E);
        scan_rowptr<<<1, blk, 0, stream>>>(deg, rowptr, cursor, N);
        fill_csr<<<gEdges, blk, 0, stream>>>(ei, cursor, csr, N, E);

        // ---- layers 1..3 (128 -> 4x32, relu)
        const float* cur = x;
        for (int l = 0; l < 3; ++l) {
            const float* Wl = (const float*)P[l * 4 + 0];
            const float* as = (const float*)P[l * 4 + 1];
            const float* ad = (const float*)P[l * 4 + 2];
            const float* bi = (const float*)P[l * 4 + 3];
            gemm128<<<dim3(1024, 2), blk, 0, stream>>>(cur, Wl, bufH, N, 128);
            node_scores<4, 32><<<(N * 4 + 255) / 256, blk, 0, stream>>>(
                bufH, as, ad, s_src, s_dst, N);
            aggregate<4, 32, 0><<<gAgg, blk, 0, stream>>>(
                bufH, s_src, s_dst, rowptr, csr, ei, bi, bufX, N, E);
            cur = bufX;
        }

        // ---- layer 4 (128 -> 1x64, sigmoid fused into d_out)
        {
            const float* Wl = (const float*)P[12];
            const float* as = (const float*)P[13];
            const float* ad = (const float*)P[14];
            const float* bi = (const float*)P[15];
            gemm128<<<dim3(1024, 1), blk, 0, stream>>>(cur, Wl, bufH, N, 64);
            node_scores<1, 64><<<(N + 255) / 256, blk, 0, stream>>>(
                bufH, as, ad, s_src, s_dst, N);
            if (b == 0)
                aggregate<1, 64, 1><<<gAgg, blk, 0, stream>>>(
                    bufH, s_src, s_dst, rowptr, csr, ei, bi, (float*)d_out, N, E);
            else
                aggregate<1, 64, 2><<<gAgg, blk, 0, stream>>>(
                    bufH, s_src, s_dst, rowptr, csr, ei, bi, (float*)d_out, N, E);
        }
    }
}

// Round 2
// 859.573 us; speedup vs baseline: 1.2766x; 1.2766x over previous
//
#include <hip/hip_runtime.h>
#include <math.h>

// ---------------------------------------------------------------------------
// dual GAT (2 branches x 4 GATConv layers), N=20000 nodes, E=320000 edges.
// R1 changes vs R0:
//  - multi-block 3-phase scan replaces the 87us single-block scan_rowptr
//  - attention scores (ss/sd) fused into the GEMM epilogue via shfl reduce
//  - GEMM register-blocked 4 rows/thread (amortize W LDS read)
// ---------------------------------------------------------------------------

#define WAVE 64

__global__ void zero_ints(int* __restrict__ p, int n) {
    int t = blockIdx.x * blockDim.x + threadIdx.x;
    if (t < n) p[t] = 0;
}

// count in-degree over E real edges + n self loops
__global__ void count_deg(const int* __restrict__ ei, int* __restrict__ deg,
                          int n, int E) {
    int t = blockIdx.x * blockDim.x + threadIdx.x;
    int total = E + n;
    if (t >= total) return;
    int dst = (t < E) ? ei[E + t] : (t - E);
    atomicAdd(&deg[dst], 1);
}

// ---- 3-phase exclusive scan --------------------------------------------
// phase 1: per-256-chunk exclusive scan (in place) + per-block total
__global__ __launch_bounds__(256) void scan_local(int* __restrict__ deg,
                                                  int* __restrict__ bsum, int n) {
    __shared__ int smem[256];
    int i = blockIdx.x * 256 + threadIdx.x;
    int v = (i < n) ? deg[i] : 0;
    smem[threadIdx.x] = v;
    __syncthreads();
    #pragma unroll
    for (int off = 1; off < 256; off <<= 1) {
        int t = (threadIdx.x >= off) ? smem[threadIdx.x - off] : 0;
        __syncthreads();
        smem[threadIdx.x] += t;
        __syncthreads();
    }
    if (i < n) deg[i] = smem[threadIdx.x] - v;   // local exclusive
    if (threadIdx.x == 255) bsum[blockIdx.x] = smem[255];
}

// phase 2: single block scans the (<=256) block sums; bsum[nb] = grand total
__global__ __launch_bounds__(256) void scan_bsum(int* __restrict__ bsum, int nb) {
    __shared__ int smem[256];
    int v = (threadIdx.x < nb) ? bsum[threadIdx.x] : 0;
    smem[threadIdx.x] = v;
    __syncthreads();
    #pragma unroll
    for (int off = 1; off < 256; off <<= 1) {
        int t = (threadIdx.x >= off) ? smem[threadIdx.x - off] : 0;
        __syncthreads();
        smem[threadIdx.x] += t;
        __syncthreads();
    }
    if (threadIdx.x < nb) bsum[threadIdx.x] = smem[threadIdx.x] - v;
    if (threadIdx.x == 255) bsum[nb] = smem[255];
}

// phase 3: add block offsets -> rowptr & cursor; rowptr[n] = total
__global__ void scan_final(const int* __restrict__ loc, const int* __restrict__ bsum,
                           int* __restrict__ rowptr, int* __restrict__ cursor,
                           int n, int nb) {
    int i = blockIdx.x * 256 + threadIdx.x;
    if (i < n) {
        int val = loc[i] + bsum[i >> 8];
        rowptr[i] = val;
        cursor[i] = val;
    } else if (i == n) {
        rowptr[n] = bsum[nb];
    }
}

__global__ void fill_csr(const int* __restrict__ ei, int* __restrict__ cursor,
                         int* __restrict__ csr_edges, int n, int E) {
    int t = blockIdx.x * blockDim.x + threadIdx.x;
    int total = E + n;
    if (t >= total) return;
    int dst = (t < E) ? ei[E + t] : (t - E);
    int pos = atomicAdd(&cursor[dst], 1);
    csr_edges[pos] = t;
}

// ---- fused GEMM + attention scores -------------------------------------
// h = x @ W (F_IN=128); also s_src[row,hd]=dot(h_row_hd, a_s[hd]), s_dst likewise.
// Block = 256 threads (4 waves). Each block owns a 64-col slice (blockIdx.y);
// each wave computes 4 rows x 64 cols per iteration (16 rows/block/iter).
// C = per-head width (32 or 64).
template <int C>
__global__ __launch_bounds__(256) void gemm_fused(
        const float* __restrict__ x, const float* __restrict__ W,
        const float* __restrict__ a_s, const float* __restrict__ a_d,
        float* __restrict__ h, float* __restrict__ s_src, float* __restrict__ s_dst,
        int n, int f_out, int heads_total) {
    __shared__ float Wlds[128 * 64];
    __shared__ float xlds[16 * 128];
    int colbase = blockIdx.y * 64;
    int lane = threadIdx.x & 63;
    int wid  = threadIdx.x >> 6;

    // stage W slice (vectorized)
    const float4* W4 = (const float4*)W;
    int fo4 = f_out >> 2;
    for (int i = threadIdx.x; i < 128 * 16; i += 256) {
        int k = i >> 4, c4 = i & 15;
        ((float4*)Wlds)[k * 16 + c4] = W4[k * fo4 + (colbase >> 2) + c4];
    }

    // per-thread attention vector elements
    int hd = colbase / C + lane / C;       // global head index
    int cc = lane % C;
    float as_l = a_s[hd * C + cc];
    float ad_l = a_d[hd * C + cc];

    const float4* x4 = (const float4*)x;
    for (int base = blockIdx.x * 16; base < n; base += gridDim.x * 16) {
        __syncthreads();
        for (int i = threadIdx.x; i < 16 * 32; i += 256) {
            int rr = base + (i >> 5);
            ((float4*)xlds)[i] = (rr < n) ? x4[rr * 32 + (i & 31)]
                                          : float4{0.f, 0.f, 0.f, 0.f};
        }
        __syncthreads();

        int r0 = wid * 4;
        float acc[4] = {0.f, 0.f, 0.f, 0.f};
        #pragma unroll 16
        for (int k = 0; k < 128; ++k) {
            float wv = Wlds[k * 64 + lane];
            acc[0] = fmaf(xlds[(r0 + 0) * 128 + k], wv, acc[0]);
            acc[1] = fmaf(xlds[(r0 + 1) * 128 + k], wv, acc[1]);
            acc[2] = fmaf(xlds[(r0 + 2) * 128 + k], wv, acc[2]);
            acc[3] = fmaf(xlds[(r0 + 3) * 128 + k], wv, acc[3]);
        }

        #pragma unroll
        for (int r = 0; r < 4; ++r) {
            int row = base + r0 + r;
            float a = acc[r];
            if (row < n) h[row * f_out + colbase + lane] = a;
            float p = a * as_l, q = a * ad_l;
            if (C == 32) {
                #pragma unroll
                for (int off = 16; off >= 1; off >>= 1) {
                    p += __shfl_xor(p, off, 32);
                    q += __shfl_xor(q, off, 32);
                }
            } else {
                #pragma unroll
                for (int off = 32; off >= 1; off >>= 1) {
                    p += __shfl_xor(p, off, 64);
                    q += __shfl_xor(q, off, 64);
                }
            }
            if (cc == 0 && row < n) {
                s_src[row * heads_total + hd] = p;
                s_dst[row * heads_total + hd] = q;
            }
        }
    }
}

// One wave per destination node. MODE 0: relu -> out (next x).
// MODE 1: 0.5*sigmoid -> d_out (store).  MODE 2: 0.5*sigmoid -> d_out (+=).
template <int HEADS, int C, int MODE>
__global__ __launch_bounds__(256) void aggregate(
        const float* __restrict__ h, const float* __restrict__ s_src,
        const float* __restrict__ s_dst, const int* __restrict__ rowptr,
        const int* __restrict__ csr_edges, const int* __restrict__ ei_src,
        const float* __restrict__ bias, float* __restrict__ out,
        int n, int E) {
    constexpr int OUTW = HEADS * C;
    constexpr int CPL = (OUTW + WAVE - 1) / WAVE;   // cols per lane (2 or 1)
    int wid = threadIdx.x >> 6;
    int lane = threadIdx.x & 63;
    int v = blockIdx.x * (blockDim.x >> 6) + wid;
    if (v >= n) return;
    int beg = rowptr[v], end = rowptr[v + 1];

    float sd[HEADS];
    #pragma unroll
    for (int hd = 0; hd < HEADS; ++hd) sd[hd] = s_dst[v * HEADS + hd];

    // pass 1: per-head max over in-edges (leaky-relu'd scores)
    float mx[HEADS];
    #pragma unroll
    for (int hd = 0; hd < HEADS; ++hd) mx[hd] = -1e30f;
    for (int i = beg + lane; i < end; i += WAVE) {
        int e = csr_edges[i];
        int s = (e < E) ? ei_src[e] : (e - E);
        #pragma unroll
        for (int hd = 0; hd < HEADS; ++hd) {
            float sc = s_src[s * HEADS + hd] + sd[hd];
            sc = (sc >= 0.f) ? sc : 0.2f * sc;
            mx[hd] = fmaxf(mx[hd], sc);
        }
    }
    #pragma unroll
    for (int hd = 0; hd < HEADS; ++hd) {
        float m = mx[hd];
        #pragma unroll
        for (int off = 32; off >= 1; off >>= 1)
            m = fmaxf(m, __shfl_xor(m, off, WAVE));
        mx[hd] = m;
    }

    // pass 2: serial over edges, lanes = output columns
    float acc[CPL], den[CPL];
    #pragma unroll
    for (int c = 0; c < CPL; ++c) { acc[c] = 0.f; den[c] = 0.f; }
    for (int i = beg; i < end; ++i) {
        int e = csr_edges[i];                    // wave-uniform
        int s = (e < E) ? ei_src[e] : (e - E);
        #pragma unroll
        for (int c = 0; c < CPL; ++c) {
            int col = lane + WAVE * c;
            int hd = col / C;
            float sc = s_src[s * HEADS + hd] + sd[hd];
            sc = (sc >= 0.f) ? sc : 0.2f * sc;
            float w = __expf(sc - mx[hd]);
            den[c] += w;
            acc[c] = fmaf(w, h[s * OUTW + col], acc[c]);
        }
    }

    #pragma unroll
    for (int c = 0; c < CPL; ++c) {
        int col = lane + WAVE * c;
        float o = acc[c] / den[c] + bias[col];
        if (MODE == 0) {
            out[v * OUTW + col] = fmaxf(o, 0.f);
        } else {
            float sg = 0.5f / (1.f + __expf(-o));
            if (MODE == 1) out[v * 64 + col] = sg;
            else           out[v * 64 + col] += sg;
        }
    }
}

extern "C" void kernel_launch(void* const* d_in, const int* in_sizes, int n_in,
                              void* d_out, int out_size, void* d_ws, size_t ws_size,
                              hipStream_t stream) {
    const int N = in_sizes[0] / 128;      // 20000
    const int E = in_sizes[1] / 2;        // 320000
    const int TOT = E + N;                // edges incl. self loops
    const int NB = (N + 255) / 256;       // scan blocks

    const float* x1 = (const float*)d_in[0];
    const int*   ei1 = (const int*)d_in[1];
    const float* x2 = (const float*)d_in[2];
    const int*   ei2 = (const int*)d_in[3];

    // workspace layout (16B-aligned chunks)
    char* w = (char*)d_ws;
    float* bufX = (float*)w;           w += (size_t)N * 128 * 4;
    float* bufH = (float*)w;           w += (size_t)N * 128 * 4;
    float* s_src = (float*)w;          w += (size_t)N * 4 * 4;
    float* s_dst = (float*)w;          w += (size_t)N * 4 * 4;
    int* rowptr = (int*)w;             w += (size_t)(N + 4) * 4;
    int* cursor = (int*)w;             w += (size_t)N * 4;
    int* deg = (int*)w;                w += (size_t)N * 4;
    int* bsum = (int*)w;               w += (size_t)(NB + 4) * 4;
    int* csr = (int*)w;                w += (size_t)TOT * 4;

    dim3 blk(256);
    int gEdges = (TOT + 255) / 256;
    int gNodes = (N + 255) / 256;
    int gFinal = (N + 256) / 256;       // covers i == n
    int gAgg = (N + 3) / 4;

    for (int b = 0; b < 2; ++b) {
        const float* x = b ? x2 : x1;
        const int* ei = b ? ei2 : ei1;
        void* const* P = d_in + (b ? 20 : 4);

        // ---- CSR build (shared across the 4 layers of this branch)
        zero_ints<<<gNodes, blk, 0, stream>>>(deg, N);
        count_deg<<<gEdges, blk, 0, stream>>>(ei, deg, N, E);
        scan_local<<<NB, blk, 0, stream>>>(deg, bsum, N);
        scan_bsum<<<1, blk, 0, stream>>>(bsum, NB);
        scan_final<<<gFinal, blk, 0, stream>>>(deg, bsum, rowptr, cursor, N, NB);
        fill_csr<<<gEdges, blk, 0, stream>>>(ei, cursor, csr, N, E);

        // ---- layers 1..3 (128 -> 4x32, relu)
        const float* cur = x;
        for (int l = 0; l < 3; ++l) {
            const float* Wl = (const float*)P[l * 4 + 0];
            const float* as = (const float*)P[l * 4 + 1];
            const float* ad = (const float*)P[l * 4 + 2];
            const float* bi = (const float*)P[l * 4 + 3];
            gemm_fused<32><<<dim3(1024, 2), blk, 0, stream>>>(
                cur, Wl, as, ad, bufH, s_src, s_dst, N, 128, 4);
            aggregate<4, 32, 0><<<gAgg, blk, 0, stream>>>(
                bufH, s_src, s_dst, rowptr, csr, ei, bi, bufX, N, E);
            cur = bufX;
        }

        // ---- layer 4 (128 -> 1x64, sigmoid fused into d_out)
        {
            const float* Wl = (const float*)P[12];
            const float* as = (const float*)P[13];
            const float* ad = (const float*)P[14];
            const float* bi = (const float*)P[15];
            gemm_fused<64><<<dim3(1024, 1), blk, 0, stream>>>(
                cur, Wl, as, ad, bufH, s_src, s_dst, N, 64, 1);
            if (b == 0)
                aggregate<1, 64, 1><<<gAgg, blk, 0, stream>>>(
                    bufH, s_src, s_dst, rowptr, csr, ei, bi, (float*)d_out, N, E);
            else
                aggregate<1, 64, 2><<<gAgg, blk, 0, stream>>>(
                    bufH, s_src, s_dst, rowptr, csr, ei, bi, (float*)d_out, N, E);
        }
    }
}

// Round 3
// 690.998 us; speedup vs baseline: 1.5880x; 1.2440x over previous
//
#include <hip/hip_runtime.h>
#include <math.h>

// ---------------------------------------------------------------------------
// dual GAT (2 branches x 4 GATConv layers), N=20000 nodes, E=320000 edges.
// R2 changes vs R1:
//  - fill_csr stores src-node id directly (kills ei_src indirection)
//  - alpha_kernel precomputes softmax weights lane-per-edge (exp off the
//    serial path; 4 exp/edge instead of 128)
//  - gather_agg: lean serial loop {s, w, fma}, 2x unroll, 2 waves/node for
//    the 128-wide layers (more memory-level parallelism)
//  - GEMM inner loop k-vectorized (float4 LDS reads)
// ---------------------------------------------------------------------------

#define WAVE 64

__global__ void zero_ints(int* __restrict__ p, int n) {
    int t = blockIdx.x * blockDim.x + threadIdx.x;
    if (t < n) p[t] = 0;
}

__global__ void count_deg(const int* __restrict__ ei, int* __restrict__ deg,
                          int n, int E) {
    int t = blockIdx.x * blockDim.x + threadIdx.x;
    int total = E + n;
    if (t >= total) return;
    int dst = (t < E) ? ei[E + t] : (t - E);
    atomicAdd(&deg[dst], 1);
}

// ---- 3-phase exclusive scan --------------------------------------------
__global__ __launch_bounds__(256) void scan_local(int* __restrict__ deg,
                                                  int* __restrict__ bsum, int n) {
    __shared__ int smem[256];
    int i = blockIdx.x * 256 + threadIdx.x;
    int v = (i < n) ? deg[i] : 0;
    smem[threadIdx.x] = v;
    __syncthreads();
    #pragma unroll
    for (int off = 1; off < 256; off <<= 1) {
        int t = (threadIdx.x >= off) ? smem[threadIdx.x - off] : 0;
        __syncthreads();
        smem[threadIdx.x] += t;
        __syncthreads();
    }
    if (i < n) deg[i] = smem[threadIdx.x] - v;   // local exclusive
    if (threadIdx.x == 255) bsum[blockIdx.x] = smem[255];
}

__global__ __launch_bounds__(256) void scan_bsum(int* __restrict__ bsum, int nb) {
    __shared__ int smem[256];
    int v = (threadIdx.x < nb) ? bsum[threadIdx.x] : 0;
    smem[threadIdx.x] = v;
    __syncthreads();
    #pragma unroll
    for (int off = 1; off < 256; off <<= 1) {
        int t = (threadIdx.x >= off) ? smem[threadIdx.x - off] : 0;
        __syncthreads();
        smem[threadIdx.x] += t;
        __syncthreads();
    }
    if (threadIdx.x < nb) bsum[threadIdx.x] = smem[threadIdx.x] - v;
    if (threadIdx.x == 255) bsum[nb] = smem[255];
}

__global__ void scan_final(const int* __restrict__ loc, const int* __restrict__ bsum,
                           int* __restrict__ rowptr, int* __restrict__ cursor,
                           int n, int nb) {
    int i = blockIdx.x * 256 + threadIdx.x;
    if (i < n) {
        int val = loc[i] + bsum[i >> 8];
        rowptr[i] = val;
        cursor[i] = val;
    } else if (i == n) {
        rowptr[n] = bsum[nb];
    }
}

// store SOURCE NODE id (not edge id) -> one less indirection downstream
__global__ void fill_csr(const int* __restrict__ ei, int* __restrict__ cursor,
                         int* __restrict__ csr_src, int n, int E) {
    int t = blockIdx.x * blockDim.x + threadIdx.x;
    int total = E + n;
    if (t >= total) return;
    int src, dst;
    if (t < E) { src = ei[t]; dst = ei[E + t]; }
    else       { src = dst = t - E; }
    int pos = atomicAdd(&cursor[dst], 1);
    csr_src[pos] = src;
}

// ---- fused GEMM + attention scores -------------------------------------
template <int C>
__global__ __launch_bounds__(256) void gemm_fused(
        const float* __restrict__ x, const float* __restrict__ W,
        const float* __restrict__ a_s, const float* __restrict__ a_d,
        float* __restrict__ h, float* __restrict__ s_src, float* __restrict__ s_dst,
        int n, int f_out, int heads_total) {
    __shared__ float Wlds[128 * 64];
    __shared__ float xlds[16 * 128];
    int colbase = blockIdx.y * 64;
    int lane = threadIdx.x & 63;
    int wid  = threadIdx.x >> 6;

    const float4* W4 = (const float4*)W;
    int fo4 = f_out >> 2;
    for (int i = threadIdx.x; i < 128 * 16; i += 256) {
        int k = i >> 4, c4 = i & 15;
        ((float4*)Wlds)[k * 16 + c4] = W4[k * fo4 + (colbase >> 2) + c4];
    }

    int hd = colbase / C + lane / C;       // global head index
    int cc = lane % C;
    float as_l = a_s[hd * C + cc];
    float ad_l = a_d[hd * C + cc];

    const float4* x4 = (const float4*)x;
    for (int base = blockIdx.x * 16; base < n; base += gridDim.x * 16) {
        __syncthreads();
        for (int i = threadIdx.x; i < 16 * 32; i += 256) {
            int rr = base + (i >> 5);
            ((float4*)xlds)[i] = (rr < n) ? x4[rr * 32 + (i & 31)]
                                          : float4{0.f, 0.f, 0.f, 0.f};
        }
        __syncthreads();

        int r0 = wid * 4;
        float acc[4] = {0.f, 0.f, 0.f, 0.f};
        const float4* xl = (const float4*)xlds;
        #pragma unroll 8
        for (int k4 = 0; k4 < 32; ++k4) {
            float4 xv0 = xl[(r0 + 0) * 32 + k4];
            float4 xv1 = xl[(r0 + 1) * 32 + k4];
            float4 xv2 = xl[(r0 + 2) * 32 + k4];
            float4 xv3 = xl[(r0 + 3) * 32 + k4];
            float w0 = Wlds[(k4 * 4 + 0) * 64 + lane];
            float w1 = Wlds[(k4 * 4 + 1) * 64 + lane];
            float w2 = Wlds[(k4 * 4 + 2) * 64 + lane];
            float w3 = Wlds[(k4 * 4 + 3) * 64 + lane];
            acc[0] = fmaf(xv0.w, w3, fmaf(xv0.z, w2, fmaf(xv0.y, w1, fmaf(xv0.x, w0, acc[0]))));
            acc[1] = fmaf(xv1.w, w3, fmaf(xv1.z, w2, fmaf(xv1.y, w1, fmaf(xv1.x, w0, acc[1]))));
            acc[2] = fmaf(xv2.w, w3, fmaf(xv2.z, w2, fmaf(xv2.y, w1, fmaf(xv2.x, w0, acc[2]))));
            acc[3] = fmaf(xv3.w, w3, fmaf(xv3.z, w2, fmaf(xv3.y, w1, fmaf(xv3.x, w0, acc[3]))));
        }

        #pragma unroll
        for (int r = 0; r < 4; ++r) {
            int row = base + r0 + r;
            float a = acc[r];
            if (row < n) h[row * f_out + colbase + lane] = a;
            float p = a * as_l, q = a * ad_l;
            if (C == 32) {
                #pragma unroll
                for (int off = 16; off >= 1; off >>= 1) {
                    p += __shfl_xor(p, off, 32);
                    q += __shfl_xor(q, off, 32);
                }
            } else {
                #pragma unroll
                for (int off = 32; off >= 1; off >>= 1) {
                    p += __shfl_xor(p, off, 64);
                    q += __shfl_xor(q, off, 64);
                }
            }
            if (cc == 0 && row < n) {
                s_src[row * heads_total + hd] = p;
                s_dst[row * heads_total + hd] = q;
            }
        }
    }
}

// ---- softmax weights, lane-per-edge ------------------------------------
// alpha[pos*HEADS+hd] = exp(lrelu(ss[src]+sd[dst]) - rowmax); dend[v,hd] = sum
template <int HEADS>
__global__ __launch_bounds__(256) void alpha_kernel(
        const float* __restrict__ s_src, const float* __restrict__ s_dst,
        const int* __restrict__ rowptr, const int* __restrict__ csr_src,
        float* __restrict__ alpha, float* __restrict__ dend, int n) {
    int wid = threadIdx.x >> 6, lane = threadIdx.x & 63;
    int v = blockIdx.x * (blockDim.x >> 6) + wid;
    if (v >= n) return;
    int beg = rowptr[v], end = rowptr[v + 1];

    float sd[HEADS];
    #pragma unroll
    for (int hd = 0; hd < HEADS; ++hd) sd[hd] = s_dst[v * HEADS + hd];

    float mx[HEADS];
    #pragma unroll
    for (int hd = 0; hd < HEADS; ++hd) mx[hd] = -1e30f;

    // pass 1: raw leaky-relu scores -> alpha (stash), track max
    for (int i = beg + lane; i < end; i += WAVE) {
        int s = csr_src[i];
        if (HEADS == 4) {
            float4 ss = ((const float4*)s_src)[s];
            float sc0 = ss.x + sd[0]; sc0 = fmaxf(sc0, 0.2f * sc0);
            float sc1 = ss.y + sd[1]; sc1 = fmaxf(sc1, 0.2f * sc1);
            float sc2 = ss.z + sd[2]; sc2 = fmaxf(sc2, 0.2f * sc2);
            float sc3 = ss.w + sd[3]; sc3 = fmaxf(sc3, 0.2f * sc3);
            ((float4*)alpha)[i] = float4{sc0, sc1, sc2, sc3};
            mx[0] = fmaxf(mx[0], sc0); mx[1] = fmaxf(mx[1], sc1);
            mx[2] = fmaxf(mx[2], sc2); mx[3] = fmaxf(mx[3], sc3);
        } else {
            float sc = s_src[s] + sd[0];
            sc = fmaxf(sc, 0.2f * sc);
            alpha[i] = sc;
            mx[0] = fmaxf(mx[0], sc);
        }
    }
    #pragma unroll
    for (int hd = 0; hd < HEADS; ++hd) {
        float m = mx[hd];
        #pragma unroll
        for (int off = 32; off >= 1; off >>= 1)
            m = fmaxf(m, __shfl_xor(m, off, WAVE));
        mx[hd] = m;
    }

    // pass 2: exp + denominator
    float den[HEADS];
    #pragma unroll
    for (int hd = 0; hd < HEADS; ++hd) den[hd] = 0.f;
    for (int i = beg + lane; i < end; i += WAVE) {
        if (HEADS == 4) {
            float4 sc = ((const float4*)alpha)[i];
            float e0 = __expf(sc.x - mx[0]);
            float e1 = __expf(sc.y - mx[1]);
            float e2 = __expf(sc.z - mx[2]);
            float e3 = __expf(sc.w - mx[3]);
            ((float4*)alpha)[i] = float4{e0, e1, e2, e3};
            den[0] += e0; den[1] += e1; den[2] += e2; den[3] += e3;
        } else {
            float e0 = __expf(alpha[i] - mx[0]);
            alpha[i] = e0;
            den[0] += e0;
        }
    }
    #pragma unroll
    for (int hd = 0; hd < HEADS; ++hd) {
        float s = den[hd];
        #pragma unroll
        for (int off = 32; off >= 1; off >>= 1)
            s += __shfl_xor(s, off, WAVE);
        den[hd] = s;
    }
    if (lane == 0) {
        #pragma unroll
        for (int hd = 0; hd < HEADS; ++hd) dend[v * HEADS + hd] = den[hd];
    }
}

// ---- gather aggregation -------------------------------------------------
// One wave per (node, 64-col half). MODE 0: relu->out; 1: .5*sigmoid store;
// 2: .5*sigmoid +=.
template <int HEADS, int C, int MODE>
__global__ __launch_bounds__(256) void gather_agg(
        const float* __restrict__ h, const float* __restrict__ alpha,
        const float* __restrict__ dend, const int* __restrict__ rowptr,
        const int* __restrict__ csr_src, const float* __restrict__ bias,
        float* __restrict__ out, int n) {
    constexpr int OUTW = HEADS * C;
    constexpr int NH = OUTW / 64;           // col-halves per node (1 or 2)
    int wid = threadIdx.x >> 6, lane = threadIdx.x & 63;
    int j = blockIdx.x * (blockDim.x >> 6) + wid;
    if (j >= n * NH) return;
    int v    = (NH == 2) ? (j >> 1) : j;
    int half = (NH == 2) ? (j & 1) : 0;
    int col = half * 64 + lane;
    int hd = col / C;
    int beg = rowptr[v], end = rowptr[v + 1];

    float acc = 0.f;
    int i = beg;
    for (; i + 1 < end; i += 2) {
        int s0 = csr_src[i];
        int s1 = csr_src[i + 1];
        float w0 = alpha[i * HEADS + hd];
        float w1 = alpha[(i + 1) * HEADS + hd];
        acc = fmaf(w0, h[(size_t)s0 * OUTW + col], acc);
        acc = fmaf(w1, h[(size_t)s1 * OUTW + col], acc);
    }
    if (i < end) {
        int s0 = csr_src[i];
        float w0 = alpha[i * HEADS + hd];
        acc = fmaf(w0, h[(size_t)s0 * OUTW + col], acc);
    }

    float o = acc / dend[v * HEADS + hd] + bias[col];
    if (MODE == 0) {
        out[v * OUTW + col] = fmaxf(o, 0.f);
    } else {
        float sg = 0.5f / (1.f + __expf(-o));
        if (MODE == 1) out[v * OUTW + col] = sg;
        else           out[v * OUTW + col] += sg;
    }
}

extern "C" void kernel_launch(void* const* d_in, const int* in_sizes, int n_in,
                              void* d_out, int out_size, void* d_ws, size_t ws_size,
                              hipStream_t stream) {
    const int N = in_sizes[0] / 128;      // 20000
    const int E = in_sizes[1] / 2;        // 320000
    const int TOT = E + N;                // edges incl. self loops
    const int NB = (N + 255) / 256;       // scan blocks

    const float* x1 = (const float*)d_in[0];
    const int*   ei1 = (const int*)d_in[1];
    const float* x2 = (const float*)d_in[2];
    const int*   ei2 = (const int*)d_in[3];

    // workspace layout (keep float4-accessed arrays 16B aligned)
    char* w = (char*)d_ws;
    float* bufX = (float*)w;           w += (size_t)N * 128 * 4;
    float* bufH = (float*)w;           w += (size_t)N * 128 * 4;
    float* alpha = (float*)w;          w += (size_t)TOT * 4 * 4;
    float* s_src = (float*)w;          w += (size_t)N * 4 * 4;
    float* s_dst = (float*)w;          w += (size_t)N * 4 * 4;
    float* dend = (float*)w;           w += (size_t)N * 4 * 4;
    int* rowptr = (int*)w;             w += (size_t)(N + 4) * 4;
    int* cursor = (int*)w;             w += (size_t)N * 4;
    int* deg = (int*)w;                w += (size_t)N * 4;
    int* csr_src = (int*)w;            w += (size_t)TOT * 4;
    int* bsum = (int*)w;               w += (size_t)(NB + 4) * 4;

    dim3 blk(256);
    int gEdges = (TOT + 255) / 256;
    int gNodes = (N + 255) / 256;
    int gFinal = (N + 256) / 256;
    int gWave = (N + 3) / 4;              // wave-per-node kernels
    int gAgg2 = (2 * N + 3) / 4;          // wave-per-(node,half)

    for (int b = 0; b < 2; ++b) {
        const float* x = b ? x2 : x1;
        const int* ei = b ? ei2 : ei1;
        void* const* P = d_in + (b ? 20 : 4);

        // ---- CSR build (shared across the 4 layers of this branch)
        zero_ints<<<gNodes, blk, 0, stream>>>(deg, N);
        count_deg<<<gEdges, blk, 0, stream>>>(ei, deg, N, E);
        scan_local<<<NB, blk, 0, stream>>>(deg, bsum, N);
        scan_bsum<<<1, blk, 0, stream>>>(bsum, NB);
        scan_final<<<gFinal, blk, 0, stream>>>(deg, bsum, rowptr, cursor, N, NB);
        fill_csr<<<gEdges, blk, 0, stream>>>(ei, cursor, csr_src, N, E);

        // ---- layers 1..3 (128 -> 4x32, relu)
        const float* cur = x;
        for (int l = 0; l < 3; ++l) {
            const float* Wl = (const float*)P[l * 4 + 0];
            const float* as = (const float*)P[l * 4 + 1];
            const float* ad = (const float*)P[l * 4 + 2];
            const float* bi = (const float*)P[l * 4 + 3];
            gemm_fused<32><<<dim3(1024, 2), blk, 0, stream>>>(
                cur, Wl, as, ad, bufH, s_src, s_dst, N, 128, 4);
            alpha_kernel<4><<<gWave, blk, 0, stream>>>(
                s_src, s_dst, rowptr, csr_src, alpha, dend, N);
            gather_agg<4, 32, 0><<<gAgg2, blk, 0, stream>>>(
                bufH, alpha, dend, rowptr, csr_src, bi, bufX, N);
            cur = bufX;
        }

        // ---- layer 4 (128 -> 1x64, sigmoid fused into d_out)
        {
            const float* Wl = (const float*)P[12];
            const float* as = (const float*)P[13];
            const float* ad = (const float*)P[14];
            const float* bi = (const float*)P[15];
            gemm_fused<64><<<dim3(1024, 1), blk, 0, stream>>>(
                cur, Wl, as, ad, bufH, s_src, s_dst, N, 64, 1);
            alpha_kernel<1><<<gWave, blk, 0, stream>>>(
                s_src, s_dst, rowptr, csr_src, alpha, dend, N);
            if (b == 0)
                gather_agg<1, 64, 1><<<gWave, blk, 0, stream>>>(
                    bufH, alpha, dend, rowptr, csr_src, bi, (float*)d_out, N);
            else
                gather_agg<1, 64, 2><<<gWave, blk, 0, stream>>>(
                    bufH, alpha, dend, rowptr, csr_src, bi, (float*)d_out, N);
        }
    }
}

// Round 4
// 525.558 us; speedup vs baseline: 2.0879x; 1.3148x over previous
//
#include <hip/hip_runtime.h>
#include <hip/hip_fp16.h>
#include <math.h>

// ---------------------------------------------------------------------------
// dual GAT (2 branches x 4 GATConv layers), N=20000 nodes, E=320000 edges.
// R3 changes vs R2:
//  - h stored fp16 (f32 accumulate in GEMM) -> gather traffic halved
//  - softmax max-subtraction dropped (scores O(1)); alpha computed
//    edge-parallel; denominator accumulated inline in the gather loop
//  - 128-wide gather: one wave/node, half2 col-pair per lane
// ---------------------------------------------------------------------------

#define WAVE 64

__global__ void zero_ints(int* __restrict__ p, int n) {
    int t = blockIdx.x * blockDim.x + threadIdx.x;
    if (t < n) p[t] = 0;
}

__global__ void count_deg(const int* __restrict__ ei, int* __restrict__ deg,
                          int n, int E) {
    int t = blockIdx.x * blockDim.x + threadIdx.x;
    int total = E + n;
    if (t >= total) return;
    int dst = (t < E) ? ei[E + t] : (t - E);
    atomicAdd(&deg[dst], 1);
}

// ---- 3-phase exclusive scan --------------------------------------------
__global__ __launch_bounds__(256) void scan_local(int* __restrict__ deg,
                                                  int* __restrict__ bsum, int n) {
    __shared__ int smem[256];
    int i = blockIdx.x * 256 + threadIdx.x;
    int v = (i < n) ? deg[i] : 0;
    smem[threadIdx.x] = v;
    __syncthreads();
    #pragma unroll
    for (int off = 1; off < 256; off <<= 1) {
        int t = (threadIdx.x >= off) ? smem[threadIdx.x - off] : 0;
        __syncthreads();
        smem[threadIdx.x] += t;
        __syncthreads();
    }
    if (i < n) deg[i] = smem[threadIdx.x] - v;   // local exclusive
    if (threadIdx.x == 255) bsum[blockIdx.x] = smem[255];
}

__global__ __launch_bounds__(256) void scan_bsum(int* __restrict__ bsum, int nb) {
    __shared__ int smem[256];
    int v = (threadIdx.x < nb) ? bsum[threadIdx.x] : 0;
    smem[threadIdx.x] = v;
    __syncthreads();
    #pragma unroll
    for (int off = 1; off < 256; off <<= 1) {
        int t = (threadIdx.x >= off) ? smem[threadIdx.x - off] : 0;
        __syncthreads();
        smem[threadIdx.x] += t;
        __syncthreads();
    }
    if (threadIdx.x < nb) bsum[threadIdx.x] = smem[threadIdx.x] - v;
    if (threadIdx.x == 255) bsum[nb] = smem[255];
}

__global__ void scan_final(const int* __restrict__ loc, const int* __restrict__ bsum,
                           int* __restrict__ rowptr, int* __restrict__ cursor,
                           int n, int nb) {
    int i = blockIdx.x * 256 + threadIdx.x;
    if (i < n) {
        int val = loc[i] + bsum[i >> 8];
        rowptr[i] = val;
        cursor[i] = val;
    } else if (i == n) {
        rowptr[n] = bsum[nb];
    }
}

// store src AND dst node ids per CSR slot
__global__ void fill_csr(const int* __restrict__ ei, int* __restrict__ cursor,
                         int* __restrict__ csr_src, int* __restrict__ csr_dst,
                         int n, int E) {
    int t = blockIdx.x * blockDim.x + threadIdx.x;
    int total = E + n;
    if (t >= total) return;
    int src, dst;
    if (t < E) { src = ei[t]; dst = ei[E + t]; }
    else       { src = dst = t - E; }
    int pos = atomicAdd(&cursor[dst], 1);
    csr_src[pos] = src;
    csr_dst[pos] = dst;
}

// ---- fused GEMM + attention scores (h stored fp16) ----------------------
template <int C>
__global__ __launch_bounds__(256) void gemm_fused(
        const float* __restrict__ x, const float* __restrict__ W,
        const float* __restrict__ a_s, const float* __restrict__ a_d,
        __half* __restrict__ h, float* __restrict__ s_src, float* __restrict__ s_dst,
        int n, int f_out, int heads_total) {
    __shared__ float Wlds[128 * 64];
    __shared__ float xlds[16 * 128];
    int colbase = blockIdx.y * 64;
    int lane = threadIdx.x & 63;
    int wid  = threadIdx.x >> 6;

    const float4* W4 = (const float4*)W;
    int fo4 = f_out >> 2;
    for (int i = threadIdx.x; i < 128 * 16; i += 256) {
        int k = i >> 4, c4 = i & 15;
        ((float4*)Wlds)[k * 16 + c4] = W4[k * fo4 + (colbase >> 2) + c4];
    }

    int hd = colbase / C + lane / C;       // global head index
    int cc = lane % C;
    float as_l = a_s[hd * C + cc];
    float ad_l = a_d[hd * C + cc];

    const float4* x4 = (const float4*)x;
    for (int base = blockIdx.x * 16; base < n; base += gridDim.x * 16) {
        __syncthreads();
        for (int i = threadIdx.x; i < 16 * 32; i += 256) {
            int rr = base + (i >> 5);
            ((float4*)xlds)[i] = (rr < n) ? x4[rr * 32 + (i & 31)]
                                          : float4{0.f, 0.f, 0.f, 0.f};
        }
        __syncthreads();

        int r0 = wid * 4;
        float acc[4] = {0.f, 0.f, 0.f, 0.f};
        const float4* xl = (const float4*)xlds;
        #pragma unroll 8
        for (int k4 = 0; k4 < 32; ++k4) {
            float4 xv0 = xl[(r0 + 0) * 32 + k4];
            float4 xv1 = xl[(r0 + 1) * 32 + k4];
            float4 xv2 = xl[(r0 + 2) * 32 + k4];
            float4 xv3 = xl[(r0 + 3) * 32 + k4];
            float w0 = Wlds[(k4 * 4 + 0) * 64 + lane];
            float w1 = Wlds[(k4 * 4 + 1) * 64 + lane];
            float w2 = Wlds[(k4 * 4 + 2) * 64 + lane];
            float w3 = Wlds[(k4 * 4 + 3) * 64 + lane];
            acc[0] = fmaf(xv0.w, w3, fmaf(xv0.z, w2, fmaf(xv0.y, w1, fmaf(xv0.x, w0, acc[0]))));
            acc[1] = fmaf(xv1.w, w3, fmaf(xv1.z, w2, fmaf(xv1.y, w1, fmaf(xv1.x, w0, acc[1]))));
            acc[2] = fmaf(xv2.w, w3, fmaf(xv2.z, w2, fmaf(xv2.y, w1, fmaf(xv2.x, w0, acc[2]))));
            acc[3] = fmaf(xv3.w, w3, fmaf(xv3.z, w2, fmaf(xv3.y, w1, fmaf(xv3.x, w0, acc[3]))));
        }

        #pragma unroll
        for (int r = 0; r < 4; ++r) {
            int row = base + r0 + r;
            float a = acc[r];
            if (row < n) h[row * f_out + colbase + lane] = __float2half(a);
            float p = a * as_l, q = a * ad_l;
            if (C == 32) {
                #pragma unroll
                for (int off = 16; off >= 1; off >>= 1) {
                    p += __shfl_xor(p, off, 32);
                    q += __shfl_xor(q, off, 32);
                }
            } else {
                #pragma unroll
                for (int off = 32; off >= 1; off >>= 1) {
                    p += __shfl_xor(p, off, 64);
                    q += __shfl_xor(q, off, 64);
                }
            }
            if (cc == 0 && row < n) {
                s_src[row * heads_total + hd] = p;
                s_dst[row * heads_total + hd] = q;
            }
        }
    }
}

// ---- edge-parallel unnormalized softmax weights -------------------------
// alpha[t,hd] = exp(lrelu(ss[src,hd] + sd[dst,hd]))  (no max: scores are O(1))
template <int HEADS>
__global__ __launch_bounds__(256) void alpha_edges(
        const float* __restrict__ s_src, const float* __restrict__ s_dst,
        const int* __restrict__ csr_src, const int* __restrict__ csr_dst,
        float* __restrict__ alpha, int tot) {
    int t = blockIdx.x * blockDim.x + threadIdx.x;
    if (t >= tot) return;
    int s = csr_src[t], d = csr_dst[t];
    if (HEADS == 4) {
        float4 ss = ((const float4*)s_src)[s];
        float4 sd = ((const float4*)s_dst)[d];
        float c0 = ss.x + sd.x; c0 = fmaxf(c0, 0.2f * c0);
        float c1 = ss.y + sd.y; c1 = fmaxf(c1, 0.2f * c1);
        float c2 = ss.z + sd.z; c2 = fmaxf(c2, 0.2f * c2);
        float c3 = ss.w + sd.w; c3 = fmaxf(c3, 0.2f * c3);
        ((float4*)alpha)[t] = float4{__expf(c0), __expf(c1), __expf(c2), __expf(c3)};
    } else {
        float c = s_src[s] + s_dst[d];
        c = fmaxf(c, 0.2f * c);
        alpha[t] = __expf(c);
    }
}

// ---- gather aggregation, 128-wide layers (4 heads x 32) -----------------
// one wave per node; lane owns col pair (2*lane, 2*lane+1) via half2 load.
__global__ __launch_bounds__(256) void gather128(
        const __half* __restrict__ h, const float* __restrict__ alpha,
        const int* __restrict__ rowptr, const int* __restrict__ csr_src,
        const float* __restrict__ bias, float* __restrict__ out, int n) {
    int wid = threadIdx.x >> 6, lane = threadIdx.x & 63;
    int v = blockIdx.x * 4 + wid;
    if (v >= n) return;
    int beg = rowptr[v], end = rowptr[v + 1];
    int hd = lane >> 4;                      // head of cols 2*lane, 2*lane+1

    const __half2* h2 = (const __half2*)h;
    float acc0 = 0.f, acc1 = 0.f, den = 0.f;
    int i = beg;
    for (; i + 1 < end; i += 2) {
        int s0 = csr_src[i];
        int s1 = csr_src[i + 1];
        float w0 = alpha[i * 4 + hd];
        float w1 = alpha[(i + 1) * 4 + hd];
        __half2 v0 = h2[(size_t)s0 * 64 + lane];
        __half2 v1 = h2[(size_t)s1 * 64 + lane];
        float2 f0 = __half22float2(v0);
        float2 f1 = __half22float2(v1);
        acc0 = fmaf(w0, f0.x, acc0); acc1 = fmaf(w0, f0.y, acc1);
        acc0 = fmaf(w1, f1.x, acc0); acc1 = fmaf(w1, f1.y, acc1);
        den += w0 + w1;
    }
    if (i < end) {
        int s0 = csr_src[i];
        float w0 = alpha[i * 4 + hd];
        float2 f0 = __half22float2(h2[(size_t)s0 * 64 + lane]);
        acc0 = fmaf(w0, f0.x, acc0); acc1 = fmaf(w0, f0.y, acc1);
        den += w0;
    }

    float inv = 1.f / den;
    float2 b2 = ((const float2*)bias)[lane];
    float o0 = fmaxf(fmaf(acc0, inv, b2.x), 0.f);
    float o1 = fmaxf(fmaf(acc1, inv, b2.y), 0.f);
    ((float2*)out)[(size_t)v * 64 + lane] = float2{o0, o1};
}

// ---- gather aggregation, layer 4 (1 head x 64) --------------------------
// MODE 1: 0.5*sigmoid store; MODE 2: 0.5*sigmoid +=
template <int MODE>
__global__ __launch_bounds__(256) void gather64(
        const __half* __restrict__ h, const float* __restrict__ alpha,
        const int* __restrict__ rowptr, const int* __restrict__ csr_src,
        const float* __restrict__ bias, float* __restrict__ out, int n) {
    int wid = threadIdx.x >> 6, lane = threadIdx.x & 63;
    int v = blockIdx.x * 4 + wid;
    if (v >= n) return;
    int beg = rowptr[v], end = rowptr[v + 1];

    float acc = 0.f, den = 0.f;
    int i = beg;
    for (; i + 1 < end; i += 2) {
        int s0 = csr_src[i];
        int s1 = csr_src[i + 1];
        float w0 = alpha[i];
        float w1 = alpha[i + 1];
        float f0 = __half2float(h[(size_t)s0 * 64 + lane]);
        float f1 = __half2float(h[(size_t)s1 * 64 + lane]);
        acc = fmaf(w0, f0, acc);
        acc = fmaf(w1, f1, acc);
        den += w0 + w1;
    }
    if (i < end) {
        int s0 = csr_src[i];
        float w0 = alpha[i];
        acc = fmaf(w0, __half2float(h[(size_t)s0 * 64 + lane]), acc);
        den += w0;
    }

    float o = acc / den + bias[lane];
    float sg = 0.5f / (1.f + __expf(-o));
    if (MODE == 1) out[(size_t)v * 64 + lane] = sg;
    else           out[(size_t)v * 64 + lane] += sg;
}

extern "C" void kernel_launch(void* const* d_in, const int* in_sizes, int n_in,
                              void* d_out, int out_size, void* d_ws, size_t ws_size,
                              hipStream_t stream) {
    const int N = in_sizes[0] / 128;      // 20000
    const int E = in_sizes[1] / 2;        // 320000
    const int TOT = E + N;                // edges incl. self loops
    const int NB = (N + 255) / 256;       // scan blocks

    const float* x1 = (const float*)d_in[0];
    const int*   ei1 = (const int*)d_in[1];
    const float* x2 = (const float*)d_in[2];
    const int*   ei2 = (const int*)d_in[3];

    // workspace layout (16B-aligned chunks)
    char* w = (char*)d_ws;
    float* bufX = (float*)w;           w += (size_t)N * 128 * 4;
    __half* bufH = (__half*)w;         w += (size_t)N * 128 * 2;
    float* alpha = (float*)w;          w += (size_t)TOT * 4 * 4;
    float* s_src = (float*)w;          w += (size_t)N * 4 * 4;
    float* s_dst = (float*)w;          w += (size_t)N * 4 * 4;
    int* rowptr = (int*)w;             w += (size_t)(N + 4) * 4;
    int* cursor = (int*)w;             w += (size_t)N * 4;
    int* deg = (int*)w;                w += (size_t)N * 4;
    int* csr_src = (int*)w;            w += (size_t)TOT * 4;
    int* csr_dst = (int*)w;            w += (size_t)TOT * 4;
    int* bsum = (int*)w;               w += (size_t)(NB + 4) * 4;

    dim3 blk(256);
    int gEdges = (TOT + 255) / 256;
    int gNodes = (N + 255) / 256;
    int gFinal = (N + 256) / 256;
    int gWave = (N + 3) / 4;              // wave-per-node kernels

    for (int b = 0; b < 2; ++b) {
        const float* x = b ? x2 : x1;
        const int* ei = b ? ei2 : ei1;
        void* const* P = d_in + (b ? 20 : 4);

        // ---- CSR build (shared across the 4 layers of this branch)
        zero_ints<<<gNodes, blk, 0, stream>>>(deg, N);
        count_deg<<<gEdges, blk, 0, stream>>>(ei, deg, N, E);
        scan_local<<<NB, blk, 0, stream>>>(deg, bsum, N);
        scan_bsum<<<1, blk, 0, stream>>>(bsum, NB);
        scan_final<<<gFinal, blk, 0, stream>>>(deg, bsum, rowptr, cursor, N, NB);
        fill_csr<<<gEdges, blk, 0, stream>>>(ei, cursor, csr_src, csr_dst, N, E);

        // ---- layers 1..3 (128 -> 4x32, relu)
        const float* cur = x;
        for (int l = 0; l < 3; ++l) {
            const float* Wl = (const float*)P[l * 4 + 0];
            const float* as = (const float*)P[l * 4 + 1];
            const float* ad = (const float*)P[l * 4 + 2];
            const float* bi = (const float*)P[l * 4 + 3];
            gemm_fused<32><<<dim3(1024, 2), blk, 0, stream>>>(
                cur, Wl, as, ad, bufH, s_src, s_dst, N, 128, 4);
            alpha_edges<4><<<gEdges, blk, 0, stream>>>(
                s_src, s_dst, csr_src, csr_dst, alpha, TOT);
            gather128<<<gWave, blk, 0, stream>>>(
                bufH, alpha, rowptr, csr_src, bi, bufX, N);
            cur = bufX;
        }

        // ---- layer 4 (128 -> 1x64, sigmoid fused into d_out)
        {
            const float* Wl = (const float*)P[12];
            const float* as = (const float*)P[13];
            const float* ad = (const float*)P[14];
            const float* bi = (const float*)P[15];
            gemm_fused<64><<<dim3(1024, 1), blk, 0, stream>>>(
                cur, Wl, as, ad, bufH, s_src, s_dst, N, 64, 1);
            alpha_edges<1><<<gEdges, blk, 0, stream>>>(
                s_src, s_dst, csr_src, csr_dst, alpha, TOT);
            if (b == 0)
                gather64<1><<<gWave, blk, 0, stream>>>(
                    bufH, alpha, rowptr, csr_src, bi, (float*)d_out, N);
            else
                gather64<2><<<gWave, blk, 0, stream>>>(
                    bufH, alpha, rowptr, csr_src, bi, (float*)d_out, N);
        }
    }
}

// Round 5
// 444.228 us; speedup vs baseline: 2.4702x; 1.1831x over previous
//
#include <hip/hip_runtime.h>
#include <hip/hip_fp16.h>
#include <math.h>

// ---------------------------------------------------------------------------
// dual GAT (2 branches x 4 GATConv layers), N=20000 nodes, E=320000 edges.
// R4 changes vs R3:
//  - alpha fused into gather (register-staged per-16-edge chunk + shfl
//    broadcast); alpha_edges kernels, alpha buffer, csr_dst all deleted
//  - gather issues all h-gathers of a chunk back-to-back (latency pipelining)
//  - branches batched into single dispatches (blockIdx.y/z = branch) for
//    CSR build, GEMMs, and layer-1..3 gathers: 36 -> 15 launches
// ---------------------------------------------------------------------------

#define WAVE 64

__global__ void zero_ints2(int* __restrict__ p, int n) {
    int t = blockIdx.x * blockDim.x + threadIdx.x;
    if (t < n) p[(size_t)blockIdx.y * n + t] = 0;
}

__global__ void count_deg2(const int* __restrict__ ei0, const int* __restrict__ ei1,
                           int* __restrict__ degb, int n, int E) {
    int t = blockIdx.x * blockDim.x + threadIdx.x;
    int total = E + n;
    if (t >= total) return;
    const int* ei = blockIdx.y ? ei1 : ei0;
    int* deg = degb + (size_t)blockIdx.y * n;
    int dst = (t < E) ? ei[E + t] : (t - E);
    atomicAdd(&deg[dst], 1);
}

// ---- 3-phase exclusive scan (batched over branches via blockIdx.y) ------
__global__ __launch_bounds__(256) void scan_local2(int* __restrict__ degb,
                                                   int* __restrict__ bsumb,
                                                   int n, int nbs) {
    __shared__ int smem[256];
    int* deg = degb + (size_t)blockIdx.y * n;
    int* bsum = bsumb + (size_t)blockIdx.y * nbs;
    int i = blockIdx.x * 256 + threadIdx.x;
    int v = (i < n) ? deg[i] : 0;
    smem[threadIdx.x] = v;
    __syncthreads();
    #pragma unroll
    for (int off = 1; off < 256; off <<= 1) {
        int t = (threadIdx.x >= off) ? smem[threadIdx.x - off] : 0;
        __syncthreads();
        smem[threadIdx.x] += t;
        __syncthreads();
    }
    if (i < n) deg[i] = smem[threadIdx.x] - v;   // local exclusive
    if (threadIdx.x == 255) bsum[blockIdx.x] = smem[255];
}

__global__ __launch_bounds__(256) void scan_bsum2(int* __restrict__ bsumb,
                                                  int nb, int nbs) {
    __shared__ int smem[256];
    int* bsum = bsumb + (size_t)blockIdx.y * nbs;
    int v = (threadIdx.x < nb) ? bsum[threadIdx.x] : 0;
    smem[threadIdx.x] = v;
    __syncthreads();
    #pragma unroll
    for (int off = 1; off < 256; off <<= 1) {
        int t = (threadIdx.x >= off) ? smem[threadIdx.x - off] : 0;
        __syncthreads();
        smem[threadIdx.x] += t;
        __syncthreads();
    }
    if (threadIdx.x < nb) bsum[threadIdx.x] = smem[threadIdx.x] - v;
    if (threadIdx.x == 255) bsum[nb] = smem[255];
}

__global__ void scan_final2(const int* __restrict__ degb, const int* __restrict__ bsumb,
                            int* __restrict__ rowptrb, int* __restrict__ cursorb,
                            int n, int nb, int nbs, int np) {
    const int* loc = degb + (size_t)blockIdx.y * n;
    const int* bsum = bsumb + (size_t)blockIdx.y * nbs;
    int* rowptr = rowptrb + (size_t)blockIdx.y * np;
    int* cursor = cursorb + (size_t)blockIdx.y * n;
    int i = blockIdx.x * 256 + threadIdx.x;
    if (i < n) {
        int val = loc[i] + bsum[i >> 8];
        rowptr[i] = val;
        cursor[i] = val;
    } else if (i == n) {
        rowptr[n] = bsum[nb];
    }
}

__global__ void fill_csr2(const int* __restrict__ ei0, const int* __restrict__ ei1,
                          int* __restrict__ cursorb, int* __restrict__ csrb,
                          int n, int E, int tot) {
    int t = blockIdx.x * blockDim.x + threadIdx.x;
    int total = E + n;
    if (t >= total) return;
    const int* ei = blockIdx.y ? ei1 : ei0;
    int* cursor = cursorb + (size_t)blockIdx.y * n;
    int* csr = csrb + (size_t)blockIdx.y * tot;
    int src, dst;
    if (t < E) { src = ei[t]; dst = ei[E + t]; }
    else       { src = dst = t - E; }
    int pos = atomicAdd(&cursor[dst], 1);
    csr[pos] = src;
}

// ---- fused GEMM + attention scores (h fp16), batched over branches ------
template <int C>
__global__ __launch_bounds__(256) void gemm_fused(
        const float* __restrict__ x0, const float* __restrict__ x1,
        const float* __restrict__ W0, const float* __restrict__ W1,
        const float* __restrict__ as0, const float* __restrict__ as1,
        const float* __restrict__ ad0, const float* __restrict__ ad1,
        __half* __restrict__ hb, float* __restrict__ ssb, float* __restrict__ sdb,
        int n, int f_out, int heads_total) {
    __shared__ float Wlds[128 * 64];
    __shared__ float xlds[16 * 128];
    int b = blockIdx.z;
    const float* x = b ? x1 : x0;
    const float* W = b ? W1 : W0;
    const float* a_s = b ? as1 : as0;
    const float* a_d = b ? ad1 : ad0;
    __half* h = hb + (size_t)b * n * 128;
    float* s_src = ssb + (size_t)b * n * 4;
    float* s_dst = sdb + (size_t)b * n * 4;

    int colbase = blockIdx.y * 64;
    int lane = threadIdx.x & 63;
    int wid  = threadIdx.x >> 6;

    const float4* W4 = (const float4*)W;
    int fo4 = f_out >> 2;
    for (int i = threadIdx.x; i < 128 * 16; i += 256) {
        int k = i >> 4, c4 = i & 15;
        ((float4*)Wlds)[k * 16 + c4] = W4[k * fo4 + (colbase >> 2) + c4];
    }

    int hd = colbase / C + lane / C;       // global head index
    int cc = lane % C;
    float as_l = a_s[hd * C + cc];
    float ad_l = a_d[hd * C + cc];

    const float4* x4 = (const float4*)x;
    int base = blockIdx.x * 16;
    {
        __syncthreads();
        for (int i = threadIdx.x; i < 16 * 32; i += 256) {
            int rr = base + (i >> 5);
            ((float4*)xlds)[i] = (rr < n) ? x4[rr * 32 + (i & 31)]
                                          : float4{0.f, 0.f, 0.f, 0.f};
        }
        __syncthreads();

        int r0 = wid * 4;
        float acc[4] = {0.f, 0.f, 0.f, 0.f};
        const float4* xl = (const float4*)xlds;
        #pragma unroll 8
        for (int k4 = 0; k4 < 32; ++k4) {
            float4 xv0 = xl[(r0 + 0) * 32 + k4];
            float4 xv1 = xl[(r0 + 1) * 32 + k4];
            float4 xv2 = xl[(r0 + 2) * 32 + k4];
            float4 xv3 = xl[(r0 + 3) * 32 + k4];
            float w0 = Wlds[(k4 * 4 + 0) * 64 + lane];
            float w1 = Wlds[(k4 * 4 + 1) * 64 + lane];
            float w2 = Wlds[(k4 * 4 + 2) * 64 + lane];
            float w3 = Wlds[(k4 * 4 + 3) * 64 + lane];
            acc[0] = fmaf(xv0.w, w3, fmaf(xv0.z, w2, fmaf(xv0.y, w1, fmaf(xv0.x, w0, acc[0]))));
            acc[1] = fmaf(xv1.w, w3, fmaf(xv1.z, w2, fmaf(xv1.y, w1, fmaf(xv1.x, w0, acc[1]))));
            acc[2] = fmaf(xv2.w, w3, fmaf(xv2.z, w2, fmaf(xv2.y, w1, fmaf(xv2.x, w0, acc[2]))));
            acc[3] = fmaf(xv3.w, w3, fmaf(xv3.z, w2, fmaf(xv3.y, w1, fmaf(xv3.x, w0, acc[3]))));
        }

        #pragma unroll
        for (int r = 0; r < 4; ++r) {
            int row = base + r0 + r;
            float a = acc[r];
            if (row < n) h[(size_t)row * f_out + colbase + lane] = __float2half(a);
            float p = a * as_l, q = a * ad_l;
            if (C == 32) {
                #pragma unroll
                for (int off = 16; off >= 1; off >>= 1) {
                    p += __shfl_xor(p, off, 32);
                    q += __shfl_xor(q, off, 32);
                }
            } else {
                #pragma unroll
                for (int off = 32; off >= 1; off >>= 1) {
                    p += __shfl_xor(p, off, 64);
                    q += __shfl_xor(q, off, 64);
                }
            }
            if (cc == 0 && row < n) {
                s_src[(size_t)row * heads_total + hd] = p;
                s_dst[(size_t)row * heads_total + hd] = q;
            }
        }
    }
}

// ---- fused alpha + gather, 128-wide layers (4 heads x 32) ---------------
// one wave per node; per 16-edge chunk: lane (hd*16+sub) computes alpha for
// edge sub / head hd; then shfl-broadcast loop with back-to-back h gathers.
__global__ __launch_bounds__(256) void gather128_f(
        const __half* __restrict__ hb, const float* __restrict__ ssb,
        const float* __restrict__ sdb, const int* __restrict__ rpb,
        const int* __restrict__ csrb, const float* __restrict__ bias0,
        const float* __restrict__ bias1, float* __restrict__ outb,
        int n, int tot, int np) {
    int b = blockIdx.z;
    const __half2* h2 = (const __half2*)(hb + (size_t)b * n * 128);
    const float* ss = ssb + (size_t)b * n * 4;
    const float* sd = sdb + (size_t)b * n * 4;
    const int* rowptr = rpb + (size_t)b * np;
    const int* csr = csrb + (size_t)b * tot;
    const float* bias = b ? bias1 : bias0;
    float* out = outb + (size_t)b * n * 128;

    int wid = threadIdx.x >> 6, lane = threadIdx.x & 63;
    int v = blockIdx.x * 4 + wid;
    if (v >= n) return;
    int beg = rowptr[v], end = rowptr[v + 1];
    int hd = lane >> 4;                    // head of this lane's col pair
    int sub = lane & 15;                   // phase-A edge slot
    float sd_h = sd[(size_t)v * 4 + hd];

    float acc0 = 0.f, acc1 = 0.f, den = 0.f;
    for (int i0 = beg; i0 < end; i0 += 16) {
        int cnt = min(16, end - i0);
        int myidx = (sub < cnt) ? csr[i0 + sub] : -1;
        float w_reg = 0.f;
        if (myidx >= 0) {
            float sc = ss[(size_t)myidx * 4 + hd] + sd_h;
            sc = fmaxf(sc, 0.2f * sc);
            w_reg = __expf(sc);
        }
        #pragma unroll 4
        for (int j = 0; j < cnt; ++j) {
            int s = __shfl(myidx, j);
            float w = __shfl(w_reg, hd * 16 + j);
            float2 f = __half22float2(h2[(size_t)s * 64 + lane]);
            acc0 = fmaf(w, f.x, acc0);
            acc1 = fmaf(w, f.y, acc1);
            den += w;
        }
    }

    float inv = 1.f / den;
    float2 b2 = ((const float2*)bias)[lane];
    float o0 = fmaxf(fmaf(acc0, inv, b2.x), 0.f);
    float o1 = fmaxf(fmaf(acc1, inv, b2.y), 0.f);
    ((float2*)out)[(size_t)v * 64 + lane] = float2{o0, o1};
}

// ---- fused alpha + gather, layer 4 (1 head x 64) ------------------------
// MODE 1: 0.5*sigmoid store; MODE 2: 0.5*sigmoid +=
template <int MODE>
__global__ __launch_bounds__(256) void gather64_f(
        const __half* __restrict__ h, const float* __restrict__ ss,
        const float* __restrict__ sd, const int* __restrict__ rowptr,
        const int* __restrict__ csr, const float* __restrict__ bias,
        float* __restrict__ out, int n) {
    int wid = threadIdx.x >> 6, lane = threadIdx.x & 63;
    int v = blockIdx.x * 4 + wid;
    if (v >= n) return;
    int beg = rowptr[v], end = rowptr[v + 1];
    float sd_v = sd[v];

    float acc = 0.f, den = 0.f;
    for (int i0 = beg; i0 < end; i0 += 64) {
        int cnt = min(64, end - i0);
        int myidx = (lane < cnt) ? csr[i0 + lane] : -1;
        float w_reg = 0.f;
        if (myidx >= 0) {
            float sc = ss[myidx] + sd_v;
            sc = fmaxf(sc, 0.2f * sc);
            w_reg = __expf(sc);
        }
        #pragma unroll 4
        for (int j = 0; j < cnt; ++j) {
            int s = __shfl(myidx, j);
            float w = __shfl(w_reg, j);
            float f = __half2float(h[(size_t)s * 64 + lane]);
            acc = fmaf(w, f, acc);
            den += w;
        }
    }

    float o = acc / den + bias[lane];
    float sg = 0.5f / (1.f + __expf(-o));
    if (MODE == 1) out[(size_t)v * 64 + lane] = sg;
    else           out[(size_t)v * 64 + lane] += sg;
}

extern "C" void kernel_launch(void* const* d_in, const int* in_sizes, int n_in,
                              void* d_out, int out_size, void* d_ws, size_t ws_size,
                              hipStream_t stream) {
    const int N = in_sizes[0] / 128;      // 20000
    const int E = in_sizes[1] / 2;        // 320000
    const int TOT = E + N;                // edges incl. self loops
    const int NB = (N + 255) / 256;       // scan blocks
    const int NP = N + 4;                 // rowptr stride
    const int NBs = NB + 8;               // bsum stride

    const float* x1 = (const float*)d_in[0];
    const int*   ei1 = (const int*)d_in[1];
    const float* x2 = (const float*)d_in[2];
    const int*   ei2 = (const int*)d_in[3];
    void* const* P0 = d_in + 4;
    void* const* P1 = d_in + 20;

    // workspace layout (16B-aligned chunks), x2 for the two branches
    char* w = (char*)d_ws;
    float* bufX = (float*)w;           w += (size_t)2 * N * 128 * 4;
    __half* bufH = (__half*)w;         w += (size_t)2 * N * 128 * 2;
    float* s_src = (float*)w;          w += (size_t)2 * N * 4 * 4;
    float* s_dst = (float*)w;          w += (size_t)2 * N * 4 * 4;
    int* rowptr = (int*)w;             w += (size_t)2 * NP * 4;
    int* cursor = (int*)w;             w += (size_t)2 * N * 4;
    int* deg = (int*)w;                w += (size_t)2 * N * 4;
    int* csr_src = (int*)w;            w += (size_t)2 * TOT * 4;
    int* bsum = (int*)w;               w += (size_t)2 * NBs * 4;

    dim3 blk(256);
    int gEdges = (TOT + 255) / 256;
    int gNodes = (N + 255) / 256;
    int gFinal = (N + 256) / 256;
    int gTile  = (N + 15) / 16;           // gemm row tiles
    int gWave  = (N + 3) / 4;             // wave-per-node kernels

    // ---- CSR build, both branches batched -------------------------------
    zero_ints2<<<dim3(gNodes, 2), blk, 0, stream>>>(deg, N);
    count_deg2<<<dim3(gEdges, 2), blk, 0, stream>>>(ei1, ei2, deg, N, E);
    scan_local2<<<dim3(NB, 2), blk, 0, stream>>>(deg, bsum, N, NBs);
    scan_bsum2<<<dim3(1, 2), blk, 0, stream>>>(bsum, NB, NBs);
    scan_final2<<<dim3(gFinal, 2), blk, 0, stream>>>(deg, bsum, rowptr, cursor,
                                                     N, NB, NBs, NP);
    fill_csr2<<<dim3(gEdges, 2), blk, 0, stream>>>(ei1, ei2, cursor, csr_src,
                                                   N, E, TOT);

    // ---- layers 1..3 (128 -> 4x32, relu), both branches batched ---------
    const float* cur0 = x1;
    const float* cur1 = x2;
    for (int l = 0; l < 3; ++l) {
        gemm_fused<32><<<dim3(gTile, 2, 2), blk, 0, stream>>>(
            cur0, cur1,
            (const float*)P0[l*4+0], (const float*)P1[l*4+0],
            (const float*)P0[l*4+1], (const float*)P1[l*4+1],
            (const float*)P0[l*4+2], (const float*)P1[l*4+2],
            bufH, s_src, s_dst, N, 128, 4);
        gather128_f<<<dim3(gWave, 1, 2), blk, 0, stream>>>(
            bufH, s_src, s_dst, rowptr, csr_src,
            (const float*)P0[l*4+3], (const float*)P1[l*4+3],
            bufX, N, TOT, NP);
        cur0 = bufX;
        cur1 = bufX + (size_t)N * 128;
    }

    // ---- layer 4 (128 -> 1x64, sigmoid fused into d_out) ----------------
    gemm_fused<64><<<dim3(gTile, 1, 2), blk, 0, stream>>>(
        cur0, cur1,
        (const float*)P0[12], (const float*)P1[12],
        (const float*)P0[13], (const float*)P1[13],
        (const float*)P0[14], (const float*)P1[14],
        bufH, s_src, s_dst, N, 64, 1);
    gather64_f<1><<<gWave, blk, 0, stream>>>(
        bufH, s_src, s_dst, rowptr, csr_src,
        (const float*)P0[15], (float*)d_out, N);
    gather64_f<2><<<gWave, blk, 0, stream>>>(
        bufH + (size_t)N * 128, s_src + (size_t)N * 4, s_dst + (size_t)N * 4,
        rowptr + NP, csr_src + (size_t)TOT,
        (const float*)P1[15], (float*)d_out, N);
}

// Round 7
// 343.166 us; speedup vs baseline: 3.1976x; 1.2945x over previous
//
#include <hip/hip_runtime.h>
#include <hip/hip_fp16.h>
#include <math.h>

// ---------------------------------------------------------------------------
// dual GAT (2 branches x 4 GATConv layers), N=20000 nodes, E=320000 edges.
// R6 = R5 with one fix: gemm_mfma's per-branch h offset is n*128 (matching
// the launch-side gather pointers), not n*fout — R5's branch-1 layer-4
// gather was reading stale layer-3 data at bufH + N*128.
// ---------------------------------------------------------------------------

#define WAVE 64

typedef _Float16 f16;
typedef f16 f16x8 __attribute__((ext_vector_type(8)));
typedef f16 f16x4 __attribute__((ext_vector_type(4)));
typedef float f32x4 __attribute__((ext_vector_type(4)));

__global__ void zero_ints2(int* __restrict__ p, int n) {
    int t = blockIdx.x * blockDim.x + threadIdx.x;
    if (t < n) p[(size_t)blockIdx.y * n + t] = 0;
}

__global__ void count_deg2(const int* __restrict__ ei0, const int* __restrict__ ei1,
                           int* __restrict__ degb, int n, int E) {
    int t = blockIdx.x * blockDim.x + threadIdx.x;
    int total = E + n;
    if (t >= total) return;
    const int* ei = blockIdx.y ? ei1 : ei0;
    int* deg = degb + (size_t)blockIdx.y * n;
    int dst = (t < E) ? ei[E + t] : (t - E);
    atomicAdd(&deg[dst], 1);
}

// ---- 3-phase exclusive scan (batched over branches via blockIdx.y) ------
__global__ __launch_bounds__(256) void scan_local2(int* __restrict__ degb,
                                                   int* __restrict__ bsumb,
                                                   int n, int nbs) {
    __shared__ int smem[256];
    int* deg = degb + (size_t)blockIdx.y * n;
    int* bsum = bsumb + (size_t)blockIdx.y * nbs;
    int i = blockIdx.x * 256 + threadIdx.x;
    int v = (i < n) ? deg[i] : 0;
    smem[threadIdx.x] = v;
    __syncthreads();
    #pragma unroll
    for (int off = 1; off < 256; off <<= 1) {
        int t = (threadIdx.x >= off) ? smem[threadIdx.x - off] : 0;
        __syncthreads();
        smem[threadIdx.x] += t;
        __syncthreads();
    }
    if (i < n) deg[i] = smem[threadIdx.x] - v;   // local exclusive
    if (threadIdx.x == 255) bsum[blockIdx.x] = smem[255];
}

__global__ __launch_bounds__(256) void scan_bsum2(int* __restrict__ bsumb,
                                                  int nb, int nbs) {
    __shared__ int smem[256];
    int* bsum = bsumb + (size_t)blockIdx.y * nbs;
    int v = (threadIdx.x < nb) ? bsum[threadIdx.x] : 0;
    smem[threadIdx.x] = v;
    __syncthreads();
    #pragma unroll
    for (int off = 1; off < 256; off <<= 1) {
        int t = (threadIdx.x >= off) ? smem[threadIdx.x - off] : 0;
        __syncthreads();
        smem[threadIdx.x] += t;
        __syncthreads();
    }
    if (threadIdx.x < nb) bsum[threadIdx.x] = smem[threadIdx.x] - v;
    if (threadIdx.x == 255) bsum[nb] = smem[255];
}

__global__ void scan_final2(const int* __restrict__ degb, const int* __restrict__ bsumb,
                            int* __restrict__ rowptrb, int* __restrict__ cursorb,
                            int n, int nb, int nbs, int np) {
    const int* loc = degb + (size_t)blockIdx.y * n;
    const int* bsum = bsumb + (size_t)blockIdx.y * nbs;
    int* rowptr = rowptrb + (size_t)blockIdx.y * np;
    int* cursor = cursorb + (size_t)blockIdx.y * n;
    int i = blockIdx.x * 256 + threadIdx.x;
    if (i < n) {
        int val = loc[i] + bsum[i >> 8];
        rowptr[i] = val;
        cursor[i] = val;
    } else if (i == n) {
        rowptr[n] = bsum[nb];
    }
}

__global__ void fill_csr2(const int* __restrict__ ei0, const int* __restrict__ ei1,
                          int* __restrict__ cursorb, int* __restrict__ csrb,
                          int n, int E, int tot) {
    int t = blockIdx.x * blockDim.x + threadIdx.x;
    int total = E + n;
    if (t >= total) return;
    const int* ei = blockIdx.y ? ei1 : ei0;
    int* cursor = cursorb + (size_t)blockIdx.y * n;
    int* csr = csrb + (size_t)blockIdx.y * tot;
    int src, dst;
    if (t < E) { src = ei[t]; dst = ei[E + t]; }
    else       { src = dst = t - E; }
    int pos = atomicAdd(&cursor[dst], 1);
    csr[pos] = src;
}

// ---- score-weight tile: wsd[b][sc][k] = dot(W[k, hd*C:...], a_{s|d}[hd]) ---
// sc<H: ss cols; H<=sc<2H: sd cols; rest zero. Output fp16 [16][128] per branch.
__global__ __launch_bounds__(256) void wsd_kernel(
        const float* __restrict__ W0, const float* __restrict__ W1,
        const float* __restrict__ as0, const float* __restrict__ as1,
        const float* __restrict__ ad0, const float* __restrict__ ad1,
        f16* __restrict__ wsd, int fout, int H, int C) {
    int b = blockIdx.y;
    const float* W = b ? W1 : W0;
    const float* a_s = b ? as1 : as0;
    const float* a_d = b ? ad1 : ad0;
    f16* out = wsd + (size_t)b * 16 * 128;
    int k = blockIdx.x * 16 + (threadIdx.x & 15);
    int sc = threadIdx.x >> 4;
    float sum = 0.f;
    if (sc < 2 * H) {
        int hd = (sc < H) ? sc : sc - H;
        const float* a = (sc < H) ? a_s : a_d;
        const float4* Wr = (const float4*)(W + (size_t)k * fout + hd * C);
        const float4* ar = (const float4*)(a + hd * C);
        for (int c = 0; c < (C >> 2); ++c) {
            float4 wv = Wr[c]; float4 av = ar[c];
            sum += wv.x * av.x + wv.y * av.y + wv.z * av.z + wv.w * av.w;
        }
    }
    out[sc * 128 + k] = (f16)sum;
}

// ---- MFMA GEMM: h = x@W (fp16 in, f32 acc, fp16 out) + score cols --------
// 4 waves/block, wave owns 16 rows; block = 64 rows x 64 cols (+16 score cols
// on the last y-slice). Persistent row loop; B-frags in registers.
__global__ __launch_bounds__(256) void gemm_mfma(
        const float* __restrict__ x0, const float* __restrict__ x1,
        const float* __restrict__ W0, const float* __restrict__ W1,
        const f16* __restrict__ wsd,
        f16* __restrict__ hb, float* __restrict__ ssb, float* __restrict__ sdb,
        int n, int fout, int H) {
    __shared__ f16 xl[64 * 136];
    __shared__ f16 wl[80 * 136];
    int b = blockIdx.z;
    const float* x = b ? x1 : x0;
    const float* W = b ? W1 : W0;
    f16* h = hb + (size_t)b * n * 128;   // branch stride fixed at n*128 (R6 fix)
    float* ss = ssb + (size_t)b * n * 4;
    float* sd = sdb + (size_t)b * n * 4;
    int colbase = blockIdx.y * 64;
    bool last = (blockIdx.y == gridDim.y - 1);
    int lane = threadIdx.x & 63, w = threadIdx.x >> 6;

    // stage W cols [colbase, colbase+64) transposed -> wl[c][k] (fp16)
    {
        int c = threadIdx.x & 63, kb = (threadIdx.x >> 6) * 32;
        #pragma unroll 8
        for (int j = 0; j < 32; ++j)
            wl[c * 136 + kb + j] = (f16)W[(size_t)(kb + j) * fout + colbase + c];
    }
    if (last) {   // stage score tile into wl rows 64..79
        int c = threadIdx.x & 15, kb = (threadIdx.x >> 4) * 8;
        *(f16x8*)&wl[(64 + c) * 136 + kb] =
            *(const f16x8*)&wsd[(size_t)b * 2048 + c * 128 + kb];
    }
    __syncthreads();

    // B-fragments to registers (ct 4 = score tile; garbage on non-last slices,
    // consumed but never stored)
    f16x8 B[5][4];
    #pragma unroll
    for (int ct = 0; ct < 5; ++ct)
        #pragma unroll
        for (int kc = 0; kc < 4; ++kc)
            B[ct][kc] = *(const f16x8*)
                &wl[(ct * 16 + (lane & 15)) * 136 + kc * 32 + (lane >> 4) * 8];

    const float4* x4 = (const float4*)x;
    for (int base = blockIdx.x * 64; base < n; base += gridDim.x * 64) {
        __syncthreads();   // previous tile's A-reads done
        {
            int r = threadIdx.x >> 2, k0 = (threadIdx.x & 3) * 32;
            int row = base + r;
            if (row < n) {
                #pragma unroll
                for (int j = 0; j < 8; ++j) {
                    float4 v = x4[(size_t)row * 32 + (k0 >> 2) + j];
                    f16x4 hv = {(f16)v.x, (f16)v.y, (f16)v.z, (f16)v.w};
                    *(f16x4*)&xl[r * 136 + k0 + 4 * j] = hv;
                }
            } else {
                f16x4 z = {(f16)0.f, (f16)0.f, (f16)0.f, (f16)0.f};
                #pragma unroll
                for (int j = 0; j < 8; ++j)
                    *(f16x4*)&xl[r * 136 + k0 + 4 * j] = z;
            }
        }
        __syncthreads();

        f16x8 A[4];
        #pragma unroll
        for (int kc = 0; kc < 4; ++kc)
            A[kc] = *(const f16x8*)
                &xl[(w * 16 + (lane & 15)) * 136 + kc * 32 + (lane >> 4) * 8];

        f32x4 acc[5];
        #pragma unroll
        for (int ct = 0; ct < 5; ++ct) acc[ct] = (f32x4){0.f, 0.f, 0.f, 0.f};
        #pragma unroll
        for (int ct = 0; ct < 5; ++ct)
            #pragma unroll
            for (int kc = 0; kc < 4; ++kc)
                acc[ct] = __builtin_amdgcn_mfma_f32_16x16x32_f16(
                    A[kc], B[ct][kc], acc[ct], 0, 0, 0);

        // epilogue: C/D layout col=lane&15, row=(lane>>4)*4+reg (verified)
        int r0 = base + w * 16 + (lane >> 4) * 4;
        int c0 = lane & 15;
        #pragma unroll
        for (int ct = 0; ct < 4; ++ct) {
            int col = colbase + ct * 16 + c0;
            #pragma unroll
            for (int j = 0; j < 4; ++j) {
                int row = r0 + j;
                if (row < n) h[(size_t)row * fout + col] = (f16)acc[ct][j];
            }
        }
        if (last) {
            #pragma unroll
            for (int j = 0; j < 4; ++j) {
                int row = r0 + j;
                if (row < n) {
                    float v = acc[4][j];
                    if (c0 < H)          ss[(size_t)row * H + c0] = v;
                    else if (c0 < 2 * H) sd[(size_t)row * H + c0 - H] = v;
                }
            }
        }
    }
}

// ---- fused alpha + gather, 128-wide layers (4 heads x 32) ---------------
__global__ __launch_bounds__(256) void gather128_f(
        const __half* __restrict__ hb, const float* __restrict__ ssb,
        const float* __restrict__ sdb, const int* __restrict__ rpb,
        const int* __restrict__ csrb, const float* __restrict__ bias0,
        const float* __restrict__ bias1, float* __restrict__ outb,
        int n, int tot, int np) {
    int b = blockIdx.z;
    const __half2* h2 = (const __half2*)(hb + (size_t)b * n * 128);
    const float* ss = ssb + (size_t)b * n * 4;
    const float* sd = sdb + (size_t)b * n * 4;
    const int* rowptr = rpb + (size_t)b * np;
    const int* csr = csrb + (size_t)b * tot;
    const float* bias = b ? bias1 : bias0;
    float* out = outb + (size_t)b * n * 128;

    int wid = threadIdx.x >> 6, lane = threadIdx.x & 63;
    int v = blockIdx.x * 4 + wid;
    if (v >= n) return;
    int beg = rowptr[v], end = rowptr[v + 1];
    int hd = lane >> 4;
    int sub = lane & 15;
    float sd_h = sd[(size_t)v * 4 + hd];

    float acc0 = 0.f, acc1 = 0.f, den = 0.f;
    for (int i0 = beg; i0 < end; i0 += 16) {
        int cnt = min(16, end - i0);
        int myidx = (sub < cnt) ? csr[i0 + sub] : -1;
        float w_reg = 0.f;
        if (myidx >= 0) {
            float sc = ss[(size_t)myidx * 4 + hd] + sd_h;
            sc = fmaxf(sc, 0.2f * sc);
            w_reg = __expf(sc);
        }
        #pragma unroll 4
        for (int j = 0; j < cnt; ++j) {
            int s = __shfl(myidx, j);
            float w = __shfl(w_reg, hd * 16 + j);
            float2 f = __half22float2(h2[(size_t)s * 64 + lane]);
            acc0 = fmaf(w, f.x, acc0);
            acc1 = fmaf(w, f.y, acc1);
            den += w;
        }
    }

    float inv = 1.f / den;
    float2 b2 = ((const float2*)bias)[lane];
    float o0 = fmaxf(fmaf(acc0, inv, b2.x), 0.f);
    float o1 = fmaxf(fmaf(acc1, inv, b2.y), 0.f);
    ((float2*)out)[(size_t)v * 64 + lane] = float2{o0, o1};
}

// ---- fused alpha + gather, layer 4 (1 head x 64) ------------------------
template <int MODE>
__global__ __launch_bounds__(256) void gather64_f(
        const __half* __restrict__ h, const float* __restrict__ ss,
        const float* __restrict__ sd, const int* __restrict__ rowptr,
        const int* __restrict__ csr, const float* __restrict__ bias,
        float* __restrict__ out, int n) {
    int wid = threadIdx.x >> 6, lane = threadIdx.x & 63;
    int v = blockIdx.x * 4 + wid;
    if (v >= n) return;
    int beg = rowptr[v], end = rowptr[v + 1];
    float sd_v = sd[v];

    float acc = 0.f, den = 0.f;
    for (int i0 = beg; i0 < end; i0 += 64) {
        int cnt = min(64, end - i0);
        int myidx = (lane < cnt) ? csr[i0 + lane] : -1;
        float w_reg = 0.f;
        if (myidx >= 0) {
            float sc = ss[myidx] + sd_v;
            sc = fmaxf(sc, 0.2f * sc);
            w_reg = __expf(sc);
        }
        #pragma unroll 4
        for (int j = 0; j < cnt; ++j) {
            int s = __shfl(myidx, j);
            float w = __shfl(w_reg, j);
            float f = __half2float(h[(size_t)s * 64 + lane]);
            acc = fmaf(w, f, acc);
            den += w;
        }
    }

    float o = acc / den + bias[lane];
    float sg = 0.5f / (1.f + __expf(-o));
    if (MODE == 1) out[(size_t)v * 64 + lane] = sg;
    else           out[(size_t)v * 64 + lane] += sg;
}

extern "C" void kernel_launch(void* const* d_in, const int* in_sizes, int n_in,
                              void* d_out, int out_size, void* d_ws, size_t ws_size,
                              hipStream_t stream) {
    const int N = in_sizes[0] / 128;      // 20000
    const int E = in_sizes[1] / 2;        // 320000
    const int TOT = E + N;                // edges incl. self loops
    const int NB = (N + 255) / 256;       // scan blocks
    const int NP = N + 4;                 // rowptr stride
    const int NBs = NB + 8;               // bsum stride

    const float* x1 = (const float*)d_in[0];
    const int*   ei1 = (const int*)d_in[1];
    const float* x2 = (const float*)d_in[2];
    const int*   ei2 = (const int*)d_in[3];
    void* const* P0 = d_in + 4;
    void* const* P1 = d_in + 20;

    // workspace layout (16B-aligned chunks), x2 for the two branches
    char* w = (char*)d_ws;
    float* bufX = (float*)w;           w += (size_t)2 * N * 128 * 4;
    f16* bufH = (f16*)w;               w += (size_t)2 * N * 128 * 2;
    float* s_src = (float*)w;          w += (size_t)2 * N * 4 * 4;
    float* s_dst = (float*)w;          w += (size_t)2 * N * 4 * 4;
    int* rowptr = (int*)w;             w += (size_t)2 * NP * 4;
    int* cursor = (int*)w;             w += (size_t)2 * N * 4;
    int* deg = (int*)w;                w += (size_t)2 * N * 4;
    int* csr_src = (int*)w;            w += (size_t)2 * TOT * 4;
    int* bsum = (int*)w;               w += (size_t)2 * NBs * 4;
    f16* wsd = (f16*)w;                w += (size_t)2 * 16 * 128 * 2;

    dim3 blk(256);
    int gEdges = (TOT + 255) / 256;
    int gNodes = (N + 255) / 256;
    int gFinal = (N + 256) / 256;
    int gWave  = (N + 3) / 4;             // wave-per-node kernels

    // ---- CSR build, both branches batched -------------------------------
    zero_ints2<<<dim3(gNodes, 2), blk, 0, stream>>>(deg, N);
    count_deg2<<<dim3(gEdges, 2), blk, 0, stream>>>(ei1, ei2, deg, N, E);
    scan_local2<<<dim3(NB, 2), blk, 0, stream>>>(deg, bsum, N, NBs);
    scan_bsum2<<<dim3(1, 2), blk, 0, stream>>>(bsum, NB, NBs);
    scan_final2<<<dim3(gFinal, 2), blk, 0, stream>>>(deg, bsum, rowptr, cursor,
                                                     N, NB, NBs, NP);
    fill_csr2<<<dim3(gEdges, 2), blk, 0, stream>>>(ei1, ei2, cursor, csr_src,
                                                   N, E, TOT);

    // ---- layers 1..3 (128 -> 4x32, relu), both branches batched ---------
    const float* cur0 = x1;
    const float* cur1 = x2;
    for (int l = 0; l < 3; ++l) {
        wsd_kernel<<<dim3(8, 2), blk, 0, stream>>>(
            (const float*)P0[l*4+0], (const float*)P1[l*4+0],
            (const float*)P0[l*4+1], (const float*)P1[l*4+1],
            (const float*)P0[l*4+2], (const float*)P1[l*4+2],
            wsd, 128, 4, 32);
        gemm_mfma<<<dim3(128, 2, 2), blk, 0, stream>>>(
            cur0, cur1,
            (const float*)P0[l*4+0], (const float*)P1[l*4+0],
            wsd, bufH, s_src, s_dst, N, 128, 4);
        gather128_f<<<dim3(gWave, 1, 2), blk, 0, stream>>>(
            (const __half*)bufH, s_src, s_dst, rowptr, csr_src,
            (const float*)P0[l*4+3], (const float*)P1[l*4+3],
            bufX, N, TOT, NP);
        cur0 = bufX;
        cur1 = bufX + (size_t)N * 128;
    }

    // ---- layer 4 (128 -> 1x64, sigmoid fused into d_out) ----------------
    wsd_kernel<<<dim3(8, 2), blk, 0, stream>>>(
        (const float*)P0[12], (const float*)P1[12],
        (const float*)P0[13], (const float*)P1[13],
        (const float*)P0[14], (const float*)P1[14],
        wsd, 64, 1, 64);
    gemm_mfma<<<dim3(128, 1, 2), blk, 0, stream>>>(
        cur0, cur1,
        (const float*)P0[12], (const float*)P1[12],
        wsd, bufH, s_src, s_dst, N, 64, 1);
    gather64_f<1><<<gWave, blk, 0, stream>>>(
        (const __half*)bufH, s_src, s_dst, rowptr, csr_src,
        (const float*)P0[15], (float*)d_out, N);
    gather64_f<2><<<gWave, blk, 0, stream>>>(
        (const __half*)(bufH + (size_t)N * 128), s_src + (size_t)N * 4,
        s_dst + (size_t)N * 4, rowptr + NP, csr_src + (size_t)TOT,
        (const float*)P1[15], (float*)d_out, N);
}

// Round 8
// 309.611 us; speedup vs baseline: 3.5442x; 1.1084x over previous
//
#include <hip/hip_runtime.h>
#include <hip/hip_fp16.h>
#include <math.h>

// ---------------------------------------------------------------------------
// dual GAT (2 branches x 4 GATConv layers), N=20000 nodes, E=320000 edges.
// R7 changes vs R6:
//  - gather128 split into per-branch dispatches (L2 working set 10.2->5.1 MB)
//  - gather output stored fp16 via nontemporal stores (doesn't evict h)
//  - inter-layer activations fp16 (GEMM templated on input type; no added
//    quantization error -- the f32->f16 conversion just moved earlier)
//  - gather inner loop: fully-unrolled 16-edge burst for full chunks
// ---------------------------------------------------------------------------

#define WAVE 64

typedef _Float16 f16;
typedef f16 f16x8 __attribute__((ext_vector_type(8)));
typedef f16 f16x4 __attribute__((ext_vector_type(4)));
typedef float f32x4 __attribute__((ext_vector_type(4)));

__global__ void zero_ints2(int* __restrict__ p, int n) {
    int t = blockIdx.x * blockDim.x + threadIdx.x;
    if (t < n) p[(size_t)blockIdx.y * n + t] = 0;
}

__global__ void count_deg2(const int* __restrict__ ei0, const int* __restrict__ ei1,
                           int* __restrict__ degb, int n, int E) {
    int t = blockIdx.x * blockDim.x + threadIdx.x;
    int total = E + n;
    if (t >= total) return;
    const int* ei = blockIdx.y ? ei1 : ei0;
    int* deg = degb + (size_t)blockIdx.y * n;
    int dst = (t < E) ? ei[E + t] : (t - E);
    atomicAdd(&deg[dst], 1);
}

// ---- 3-phase exclusive scan (batched over branches via blockIdx.y) ------
__global__ __launch_bounds__(256) void scan_local2(int* __restrict__ degb,
                                                   int* __restrict__ bsumb,
                                                   int n, int nbs) {
    __shared__ int smem[256];
    int* deg = degb + (size_t)blockIdx.y * n;
    int* bsum = bsumb + (size_t)blockIdx.y * nbs;
    int i = blockIdx.x * 256 + threadIdx.x;
    int v = (i < n) ? deg[i] : 0;
    smem[threadIdx.x] = v;
    __syncthreads();
    #pragma unroll
    for (int off = 1; off < 256; off <<= 1) {
        int t = (threadIdx.x >= off) ? smem[threadIdx.x - off] : 0;
        __syncthreads();
        smem[threadIdx.x] += t;
        __syncthreads();
    }
    if (i < n) deg[i] = smem[threadIdx.x] - v;   // local exclusive
    if (threadIdx.x == 255) bsum[blockIdx.x] = smem[255];
}

__global__ __launch_bounds__(256) void scan_bsum2(int* __restrict__ bsumb,
                                                  int nb, int nbs) {
    __shared__ int smem[256];
    int* bsum = bsumb + (size_t)blockIdx.y * nbs;
    int v = (threadIdx.x < nb) ? bsum[threadIdx.x] : 0;
    smem[threadIdx.x] = v;
    __syncthreads();
    #pragma unroll
    for (int off = 1; off < 256; off <<= 1) {
        int t = (threadIdx.x >= off) ? smem[threadIdx.x - off] : 0;
        __syncthreads();
        smem[threadIdx.x] += t;
        __syncthreads();
    }
    if (threadIdx.x < nb) bsum[threadIdx.x] = smem[threadIdx.x] - v;
    if (threadIdx.x == 255) bsum[nb] = smem[255];
}

__global__ void scan_final2(const int* __restrict__ degb, const int* __restrict__ bsumb,
                            int* __restrict__ rowptrb, int* __restrict__ cursorb,
                            int n, int nb, int nbs, int np) {
    const int* loc = degb + (size_t)blockIdx.y * n;
    const int* bsum = bsumb + (size_t)blockIdx.y * nbs;
    int* rowptr = rowptrb + (size_t)blockIdx.y * np;
    int* cursor = cursorb + (size_t)blockIdx.y * n;
    int i = blockIdx.x * 256 + threadIdx.x;
    if (i < n) {
        int val = loc[i] + bsum[i >> 8];
        rowptr[i] = val;
        cursor[i] = val;
    } else if (i == n) {
        rowptr[n] = bsum[nb];
    }
}

__global__ void fill_csr2(const int* __restrict__ ei0, const int* __restrict__ ei1,
                          int* __restrict__ cursorb, int* __restrict__ csrb,
                          int n, int E, int tot) {
    int t = blockIdx.x * blockDim.x + threadIdx.x;
    int total = E + n;
    if (t >= total) return;
    const int* ei = blockIdx.y ? ei1 : ei0;
    int* cursor = cursorb + (size_t)blockIdx.y * n;
    int* csr = csrb + (size_t)blockIdx.y * tot;
    int src, dst;
    if (t < E) { src = ei[t]; dst = ei[E + t]; }
    else       { src = dst = t - E; }
    int pos = atomicAdd(&cursor[dst], 1);
    csr[pos] = src;
}

// ---- score-weight tile: wsd[b][sc][k] = dot(W[k, hd*C:...], a_{s|d}[hd]) ---
__global__ __launch_bounds__(256) void wsd_kernel(
        const float* __restrict__ W0, const float* __restrict__ W1,
        const float* __restrict__ as0, const float* __restrict__ as1,
        const float* __restrict__ ad0, const float* __restrict__ ad1,
        f16* __restrict__ wsd, int fout, int H, int C) {
    int b = blockIdx.y;
    const float* W = b ? W1 : W0;
    const float* a_s = b ? as1 : as0;
    const float* a_d = b ? ad1 : ad0;
    f16* out = wsd + (size_t)b * 16 * 128;
    int k = blockIdx.x * 16 + (threadIdx.x & 15);
    int sc = threadIdx.x >> 4;
    float sum = 0.f;
    if (sc < 2 * H) {
        int hd = (sc < H) ? sc : sc - H;
        const float* a = (sc < H) ? a_s : a_d;
        const float4* Wr = (const float4*)(W + (size_t)k * fout + hd * C);
        const float4* ar = (const float4*)(a + hd * C);
        for (int c = 0; c < (C >> 2); ++c) {
            float4 wv = Wr[c]; float4 av = ar[c];
            sum += wv.x * av.x + wv.y * av.y + wv.z * av.z + wv.w * av.w;
        }
    }
    out[sc * 128 + k] = (f16)sum;
}

// ---- MFMA GEMM: h = x@W (f32 acc, fp16 out) + score cols ----------------
// XT = float (layer 1) or f16 (layers 2..4, reading prev fp16 activations).
template <typename XT>
__global__ __launch_bounds__(256) void gemm_mfma(
        const XT* __restrict__ x0, const XT* __restrict__ x1,
        const float* __restrict__ W0, const float* __restrict__ W1,
        const f16* __restrict__ wsd,
        f16* __restrict__ hb, float* __restrict__ ssb, float* __restrict__ sdb,
        int n, int fout, int H) {
    __shared__ f16 xl[64 * 136];
    __shared__ f16 wl[80 * 136];
    int b = blockIdx.z;
    const XT* x = b ? x1 : x0;
    const float* W = b ? W1 : W0;
    f16* h = hb + (size_t)b * n * 128;
    float* ss = ssb + (size_t)b * n * 4;
    float* sd = sdb + (size_t)b * n * 4;
    int colbase = blockIdx.y * 64;
    bool last = (blockIdx.y == gridDim.y - 1);
    int lane = threadIdx.x & 63, w = threadIdx.x >> 6;

    // stage W cols [colbase, colbase+64) transposed -> wl[c][k] (fp16)
    {
        int c = threadIdx.x & 63, kb = (threadIdx.x >> 6) * 32;
        #pragma unroll 8
        for (int j = 0; j < 32; ++j)
            wl[c * 136 + kb + j] = (f16)W[(size_t)(kb + j) * fout + colbase + c];
    }
    if (last) {   // stage score tile into wl rows 64..79
        int c = threadIdx.x & 15, kb = (threadIdx.x >> 4) * 8;
        *(f16x8*)&wl[(64 + c) * 136 + kb] =
            *(const f16x8*)&wsd[(size_t)b * 2048 + c * 128 + kb];
    }
    __syncthreads();

    f16x8 B[5][4];
    #pragma unroll
    for (int ct = 0; ct < 5; ++ct)
        #pragma unroll
        for (int kc = 0; kc < 4; ++kc)
            B[ct][kc] = *(const f16x8*)
                &wl[(ct * 16 + (lane & 15)) * 136 + kc * 32 + (lane >> 4) * 8];

    for (int base = blockIdx.x * 64; base < n; base += gridDim.x * 64) {
        __syncthreads();   // previous tile's A-reads done
        {
            int r = threadIdx.x >> 2, k0 = (threadIdx.x & 3) * 32;
            int row = base + r;
            if (row < n) {
                if constexpr (sizeof(XT) == 4) {
                    const float4* x4 = (const float4*)x;
                    #pragma unroll
                    for (int j = 0; j < 8; ++j) {
                        float4 v = x4[(size_t)row * 32 + (k0 >> 2) + j];
                        f16x4 hv = {(f16)v.x, (f16)v.y, (f16)v.z, (f16)v.w};
                        *(f16x4*)&xl[r * 136 + k0 + 4 * j] = hv;
                    }
                } else {
                    const f16x8* x8 = (const f16x8*)x;
                    #pragma unroll
                    for (int j = 0; j < 4; ++j)
                        *(f16x8*)&xl[r * 136 + k0 + 8 * j] =
                            x8[(size_t)row * 16 + (k0 >> 3) + j];
                }
            } else {
                f16x4 z = {(f16)0.f, (f16)0.f, (f16)0.f, (f16)0.f};
                #pragma unroll
                for (int j = 0; j < 8; ++j)
                    *(f16x4*)&xl[r * 136 + k0 + 4 * j] = z;
            }
        }
        __syncthreads();

        f16x8 A[4];
        #pragma unroll
        for (int kc = 0; kc < 4; ++kc)
            A[kc] = *(const f16x8*)
                &xl[(w * 16 + (lane & 15)) * 136 + kc * 32 + (lane >> 4) * 8];

        f32x4 acc[5];
        #pragma unroll
        for (int ct = 0; ct < 5; ++ct) acc[ct] = (f32x4){0.f, 0.f, 0.f, 0.f};
        #pragma unroll
        for (int ct = 0; ct < 5; ++ct)
            #pragma unroll
            for (int kc = 0; kc < 4; ++kc)
                acc[ct] = __builtin_amdgcn_mfma_f32_16x16x32_f16(
                    A[kc], B[ct][kc], acc[ct], 0, 0, 0);

        // epilogue: C/D layout col=lane&15, row=(lane>>4)*4+reg (verified)
        int r0 = base + w * 16 + (lane >> 4) * 4;
        int c0 = lane & 15;
        #pragma unroll
        for (int ct = 0; ct < 4; ++ct) {
            int col = colbase + ct * 16 + c0;
            #pragma unroll
            for (int j = 0; j < 4; ++j) {
                int row = r0 + j;
                if (row < n) h[(size_t)row * fout + col] = (f16)acc[ct][j];
            }
        }
        if (last) {
            #pragma unroll
            for (int j = 0; j < 4; ++j) {
                int row = r0 + j;
                if (row < n) {
                    float v = acc[4][j];
                    if (c0 < H)          ss[(size_t)row * H + c0] = v;
                    else if (c0 < 2 * H) sd[(size_t)row * H + c0 - H] = v;
                }
            }
        }
    }
}

// ---- fused alpha + gather, 128-wide layers (4 heads x 32) ---------------
// one dispatch per branch; fp16 relu'd output via nontemporal stores.
__global__ __launch_bounds__(256) void gather128_f(
        const __half2* __restrict__ h2, const float* __restrict__ ss,
        const float* __restrict__ sd, const int* __restrict__ rowptr,
        const int* __restrict__ csr, const float* __restrict__ bias,
        f16* __restrict__ out, int n) {
    int wid = threadIdx.x >> 6, lane = threadIdx.x & 63;
    int v = blockIdx.x * 4 + wid;
    if (v >= n) return;
    int beg = rowptr[v], end = rowptr[v + 1];
    int hd = lane >> 4;
    int sub = lane & 15;
    int hd16 = hd * 16;
    float sd_h = sd[v * 4 + hd];

    float acc0 = 0.f, acc1 = 0.f, den = 0.f;
    int i0 = beg;
    // full 16-edge chunks: unrolled burst (16 gathers in flight)
    for (; i0 + 16 <= end; i0 += 16) {
        int myidx = csr[i0 + sub];
        float sc = ss[myidx * 4 + hd] + sd_h;
        sc = fmaxf(sc, 0.2f * sc);
        float w_reg = __expf(sc);
        #pragma unroll
        for (int j = 0; j < 16; ++j) {
            int s = __shfl(myidx, j);
            float w = __shfl(w_reg, hd16 + j);
            float2 f = __half22float2(h2[s * 64 + lane]);
            acc0 = fmaf(w, f.x, acc0);
            acc1 = fmaf(w, f.y, acc1);
            den += w;
        }
    }
    // tail
    int rem = end - i0;
    if (rem > 0) {
        int myidx = (sub < rem) ? csr[i0 + sub] : -1;
        float w_reg = 0.f;
        if (myidx >= 0) {
            float sc = ss[myidx * 4 + hd] + sd_h;
            sc = fmaxf(sc, 0.2f * sc);
            w_reg = __expf(sc);
        }
        #pragma unroll 4
        for (int j = 0; j < rem; ++j) {
            int s = __shfl(myidx, j);
            float w = __shfl(w_reg, hd16 + j);
            float2 f = __half22float2(h2[s * 64 + lane]);
            acc0 = fmaf(w, f.x, acc0);
            acc1 = fmaf(w, f.y, acc1);
            den += w;
        }
    }

    float inv = 1.f / den;
    float2 b2 = ((const float2*)bias)[lane];
    float o0 = fmaxf(fmaf(acc0, inv, b2.x), 0.f);
    float o1 = fmaxf(fmaf(acc1, inv, b2.y), 0.f);
    __half2 ov = __floats2half2_rn(o0, o1);
    __builtin_nontemporal_store(*(unsigned int*)&ov,
                                (unsigned int*)&out[v * 128 + 2 * lane]);
}

// ---- fused alpha + gather, layer 4 (1 head x 64) ------------------------
template <int MODE>
__global__ __launch_bounds__(256) void gather64_f(
        const __half* __restrict__ h, const float* __restrict__ ss,
        const float* __restrict__ sd, const int* __restrict__ rowptr,
        const int* __restrict__ csr, const float* __restrict__ bias,
        float* __restrict__ out, int n) {
    int wid = threadIdx.x >> 6, lane = threadIdx.x & 63;
    int v = blockIdx.x * 4 + wid;
    if (v >= n) return;
    int beg = rowptr[v], end = rowptr[v + 1];
    int sub = lane & 15;
    float sd_v = sd[v];

    float acc = 0.f, den = 0.f;
    int i0 = beg;
    for (; i0 + 16 <= end; i0 += 16) {
        int myidx = csr[i0 + sub];
        float sc = ss[myidx] + sd_v;
        sc = fmaxf(sc, 0.2f * sc);
        float w_reg = __expf(sc);
        #pragma unroll
        for (int j = 0; j < 16; ++j) {
            int s = __shfl(myidx, j);
            float w = __shfl(w_reg, j);
            float f = __half2float(h[s * 64 + lane]);
            acc = fmaf(w, f, acc);
            den += w;
        }
    }
    int rem = end - i0;
    if (rem > 0) {
        int myidx = (sub < rem) ? csr[i0 + sub] : -1;
        float w_reg = 0.f;
        if (myidx >= 0) {
            float sc = ss[myidx] + sd_v;
            sc = fmaxf(sc, 0.2f * sc);
            w_reg = __expf(sc);
        }
        #pragma unroll 4
        for (int j = 0; j < rem; ++j) {
            int s = __shfl(myidx, j);
            float w = __shfl(w_reg, j);
            float f = __half2float(h[s * 64 + lane]);
            acc = fmaf(w, f, acc);
            den += w;
        }
    }

    float o = acc / den + bias[lane];
    float sg = 0.5f / (1.f + __expf(-o));
    if (MODE == 1) out[(size_t)v * 64 + lane] = sg;
    else           out[(size_t)v * 64 + lane] += sg;
}

extern "C" void kernel_launch(void* const* d_in, const int* in_sizes, int n_in,
                              void* d_out, int out_size, void* d_ws, size_t ws_size,
                              hipStream_t stream) {
    const int N = in_sizes[0] / 128;      // 20000
    const int E = in_sizes[1] / 2;        // 320000
    const int TOT = E + N;                // edges incl. self loops
    const int NB = (N + 255) / 256;       // scan blocks
    const int NP = N + 4;                 // rowptr stride
    const int NBs = NB + 8;               // bsum stride

    const float* x1 = (const float*)d_in[0];
    const int*   ei1 = (const int*)d_in[1];
    const float* x2 = (const float*)d_in[2];
    const int*   ei2 = (const int*)d_in[3];
    void* const* P0 = d_in + 4;
    void* const* P1 = d_in + 20;

    // workspace layout (16B-aligned chunks), x2 for the two branches
    char* w = (char*)d_ws;
    f16* bufX = (f16*)w;               w += (size_t)2 * N * 128 * 2;   // fp16 activations
    f16* bufH = (f16*)w;               w += (size_t)2 * N * 128 * 2;
    float* s_src = (float*)w;          w += (size_t)2 * N * 4 * 4;
    float* s_dst = (float*)w;          w += (size_t)2 * N * 4 * 4;
    int* rowptr = (int*)w;             w += (size_t)2 * NP * 4;
    int* cursor = (int*)w;             w += (size_t)2 * N * 4;
    int* deg = (int*)w;                w += (size_t)2 * N * 4;
    int* csr_src = (int*)w;            w += (size_t)2 * TOT * 4;
    int* bsum = (int*)w;               w += (size_t)2 * NBs * 4;
    f16* wsd = (f16*)w;                w += (size_t)2 * 16 * 128 * 2;

    dim3 blk(256);
    int gEdges = (TOT + 255) / 256;
    int gNodes = (N + 255) / 256;
    int gFinal = (N + 256) / 256;
    int gWave  = (N + 3) / 4;             // wave-per-node kernels

    // ---- CSR build, both branches batched -------------------------------
    zero_ints2<<<dim3(gNodes, 2), blk, 0, stream>>>(deg, N);
    count_deg2<<<dim3(gEdges, 2), blk, 0, stream>>>(ei1, ei2, deg, N, E);
    scan_local2<<<dim3(NB, 2), blk, 0, stream>>>(deg, bsum, N, NBs);
    scan_bsum2<<<dim3(1, 2), blk, 0, stream>>>(bsum, NB, NBs);
    scan_final2<<<dim3(gFinal, 2), blk, 0, stream>>>(deg, bsum, rowptr, cursor,
                                                     N, NB, NBs, NP);
    fill_csr2<<<dim3(gEdges, 2), blk, 0, stream>>>(ei1, ei2, cursor, csr_src,
                                                   N, E, TOT);

    // ---- layers 1..3 (128 -> 4x32, relu), gathers per-branch ------------
    for (int l = 0; l < 3; ++l) {
        wsd_kernel<<<dim3(8, 2), blk, 0, stream>>>(
            (const float*)P0[l*4+0], (const float*)P1[l*4+0],
            (const float*)P0[l*4+1], (const float*)P1[l*4+1],
            (const float*)P0[l*4+2], (const float*)P1[l*4+2],
            wsd, 128, 4, 32);
        if (l == 0)
            gemm_mfma<float><<<dim3(128, 2, 2), blk, 0, stream>>>(
                x1, x2,
                (const float*)P0[0], (const float*)P1[0],
                wsd, bufH, s_src, s_dst, N, 128, 4);
        else
            gemm_mfma<f16><<<dim3(128, 2, 2), blk, 0, stream>>>(
                bufX, bufX + (size_t)N * 128,
                (const float*)P0[l*4+0], (const float*)P1[l*4+0],
                wsd, bufH, s_src, s_dst, N, 128, 4);
        for (int b = 0; b < 2; ++b)
            gather128_f<<<gWave, blk, 0, stream>>>(
                (const __half2*)(bufH + (size_t)b * N * 128),
                s_src + (size_t)b * N * 4, s_dst + (size_t)b * N * 4,
                rowptr + (size_t)b * NP, csr_src + (size_t)b * TOT,
                (const float*)(b ? P1[l*4+3] : P0[l*4+3]),
                bufX + (size_t)b * N * 128, N);
    }

    // ---- layer 4 (128 -> 1x64, sigmoid fused into d_out) ----------------
    wsd_kernel<<<dim3(8, 2), blk, 0, stream>>>(
        (const float*)P0[12], (const float*)P1[12],
        (const float*)P0[13], (const float*)P1[13],
        (const float*)P0[14], (const float*)P1[14],
        wsd, 64, 1, 64);
    gemm_mfma<f16><<<dim3(128, 1, 2), blk, 0, stream>>>(
        bufX, bufX + (size_t)N * 128,
        (const float*)P0[12], (const float*)P1[12],
        wsd, bufH, s_src, s_dst, N, 64, 1);
    gather64_f<1><<<gWave, blk, 0, stream>>>(
        (const __half*)bufH, s_src, s_dst, rowptr, csr_src,
        (const float*)P0[15], (float*)d_out, N);
    gather64_f<2><<<gWave, blk, 0, stream>>>(
        (const __half*)(bufH + (size_t)N * 128), s_src + (size_t)N * 4,
        s_dst + (size_t)N * 4, rowptr + NP, csr_src + (size_t)TOT,
        (const float*)P1[15], (float*)d_out, N);
}